// Round 11
// baseline (1282.863 us; speedup 1.0000x reference)
//
#include <hip/hip_runtime.h>

#define BB 8
#define TT 160
#define EE 300
#define HH 128
#define D2 256
#define G3 384
#define PSTR 40   // padded LDS row stride (shorts) for P tiles

typedef __attribute__((ext_vector_type(8))) short bf16x8;
typedef __attribute__((ext_vector_type(4))) float floatx4;

__device__ inline float fsigmoid(float x){ return 1.f/(1.f+__expf(-x)); }
__device__ inline float ftanh(float x){ return 2.f*fsigmoid(2.f*x) - 1.f; }

// truncation split: x ~= hi + lo, each bf16; combined rel err <= ~2^-16
__device__ inline void split2(float x, unsigned short& hi, unsigned short& lo){
  unsigned ux = __float_as_uint(x);
  hi = (unsigned short)(ux>>16);
  float r = x - __uint_as_float(ux & 0xFFFF0000u);
  lo = (unsigned short)(__float_as_uint(r)>>16);
}

// ---------------- embedding gather ----------------
__global__ __launch_bounds__(256) void k_embed(const int* ta, const int* tb,
    const float* emb, float* ep, float* ec){
  const int idx = blockIdx.x*256 + threadIdx.x;
  const int per = BB*TT*EE;
  if (idx < per){
    const int e = idx % EE, bt = idx / EE;
    ep[idx] = emb[(long)ta[bt]*EE + e];
  } else {
    const int j = idx - per;
    const int e = j % EE, bt = j / EE;
    ec[j] = emb[(long)tb[bt]*EE + e];
  }
}

// ---------------- hi/lo bf16 split of hp & hc ----------------
__global__ __launch_bounds__(256) void k_splitarr(const float* a, const float* b, int n,
    unsigned short* ahi, unsigned short* alo, unsigned short* bhi, unsigned short* blo){
  const int idx = blockIdx.x*256 + threadIdx.x;
  if (idx < n){
    split2(a[idx], ahi[idx], alo[idx]);
    split2(b[idx], bhi[idx], blo[idx]);
  }
}

// ---------------- weight pre-split: W[N x K](f32) -> hi/lo bf16 [N x Kp], zero-padded ----------------
struct SplitJob { const float* W; unsigned short* hi; unsigned short* lo; int n; int K; int Kp; };
struct SplitJobs { SplitJob j[12]; };

__global__ __launch_bounds__(256) void k_splitw(SplitJobs jobs){
  const SplitJob J = jobs.j[blockIdx.z];
  const int idx = blockIdx.x*256 + threadIdx.x;
  if (idx >= J.n) return;
  const int row = idx / J.Kp, k = idx - row*J.Kp;
  const float v = (k < J.K) ? J.W[(long)row*J.K + k] : 0.f;
  split2(v, J.hi[idx], J.lo[idx]);
}

// ---------------- MFMA GEMM with pre-split W: C = A(f32) @ W^T + bias ----------------
struct GemmSJob {
  const float* A; const unsigned short* Whi; const unsigned short* Wlo; const float* bias;
  float* C; int N; int K; int Kp;
};
struct GemmSJobs { GemmSJob j[6]; };

__global__ __launch_bounds__(256) void k_gemmS(GemmSJobs jobs){
  const GemmSJob J = jobs.j[blockIdx.z];
  const int tid = threadIdx.x;
  const int lane = tid & 63, w = tid >> 6;
  const int l15 = lane & 15, q = lane >> 4;
  const int n0 = blockIdx.x * 64;
  if (n0 >= J.N) return;
  const int K = J.K, Kp = J.Kp;
  const long mrow = blockIdx.y*64 + w*16 + l15;
  const float* Arow = J.A + mrow*K;
  floatx4 acc[4];
  #pragma unroll
  for (int t=0;t<4;t++) acc[t] = (floatx4)0.f;
  const int nch = (K+31)>>5;
  for (int kc=0; kc<nch; kc++){
    const int k0 = kc<<5;
    const int kb = k0 + q*8;
    float av[8];
    if (k0+32 <= K){
      const floatx4 a0 = *(const floatx4*)(Arow+kb);
      const floatx4 a1 = *(const floatx4*)(Arow+kb+4);
      av[0]=a0[0];av[1]=a0[1];av[2]=a0[2];av[3]=a0[3];
      av[4]=a1[0];av[5]=a1[1];av[6]=a1[2];av[7]=a1[3];
    } else {
      #pragma unroll
      for (int j=0;j<8;j++){ const int k=kb+j; av[j] = (k<K)? Arow[k] : 0.f; }
    }
    union { bf16x8 v; unsigned short u[8]; } ahi, alo;
    #pragma unroll
    for (int j=0;j<8;j++) split2(av[j], ahi.u[j], alo.u[j]);
    #pragma unroll
    for (int t=0;t<4;t++){
      const int n = n0 + t*16 + l15;
      const long wo = (long)n*Kp + kb;
      union { bf16x8 v; uint4 d; } whi, wlo;
      whi.d = *(const uint4*)(J.Whi + wo);
      wlo.d = *(const uint4*)(J.Wlo + wo);
      acc[t] = __builtin_amdgcn_mfma_f32_16x16x32_bf16(ahi.v, whi.v, acc[t], 0,0,0);
      acc[t] = __builtin_amdgcn_mfma_f32_16x16x32_bf16(ahi.v, wlo.v, acc[t], 0,0,0);
      acc[t] = __builtin_amdgcn_mfma_f32_16x16x32_bf16(alo.v, whi.v, acc[t], 0,0,0);
    }
  }
  const long rbase = blockIdx.y*64 + w*16 + q*4;
  #pragma unroll
  for (int t=0;t<4;t++){
    const int n = n0 + t*16 + l15;
    const float bv = J.bias ? J.bias[n] : 0.f;
    #pragma unroll
    for (int r=0;r<4;r++)
      J.C[(rbase+r)*(long)J.N + n] = acc[t][r] + bv;
  }
}

// ---------------- GRU scan v5: batch-packed MFMA; one block per direction ----------------
// All 8 batches as B-operand columns (col=lane&15 -> batch, cols 8..15 duplicate/ignored).
// Wave w owns gate-tiles {w, 8+w, 16+w}; A = Whh pre-split hi/lo in regs (96 VGPR, reused 160 steps).
// h kept pre-split hi/lo in LDS (B-read = 2 ds_read_b128 per kc; no inner splits, no shuffles).
// xg staged in 2-step LDS chunks; h flushed via LDS buffer -> inner barriers are lgkm-only mostly.
#define GCH 2
struct GruJob { const float* xg; const float* Whh; const float* bhh; float* out; int ocol; int rev; };
struct GruJobs { GruJob j[4]; };

__global__ __launch_bounds__(512,1) void k_gru(GruJobs jobs){
  const GruJob J = jobs.j[blockIdx.x];
  const int tid = threadIdx.x;
  const int lane = tid & 63, w = tid >> 6;   // 8 waves
  const int l15 = lane & 15, q = lane >> 4;
  const int b = l15 & 7;
  const bool act = (l15 < 8);
  __shared__ float xgt[GCH][BB][G3];            // 24576 B
  __shared__ float hbuf[GCH][BB][HH];           // 8192 B
  __shared__ unsigned short hhi[2][BB][HH];     // 4096 B
  __shared__ unsigned short hlo[2][BB][HH];     // 4096 B

  union BF { bf16x8 v; unsigned short u[8]; uint4 d; };
  BF Ah[3][4], Al[3][4];
  #pragma unroll
  for (int g=0; g<3; g++){
    const float* wr = J.Whh + (long)(g*HH + w*16 + l15)*HH;
    #pragma unroll
    for (int kc=0; kc<4; kc++){
      const floatx4 w0 = *(const floatx4*)(wr + kc*32 + q*8);
      const floatx4 w1 = *(const floatx4*)(wr + kc*32 + q*8 + 4);
      #pragma unroll
      for (int jj=0; jj<4; jj++){
        split2(w0[jj], Ah[g][kc].u[jj],   Al[g][kc].u[jj]);
        split2(w1[jj], Ah[g][kc].u[4+jj], Al[g][kc].u[4+jj]);
      }
    }
  }
  const int u0 = w*16 + q*4;   // this thread's h-unit base
  const floatx4 bhr = *(const floatx4*)(J.bhh + u0);
  const floatx4 bhz = *(const floatx4*)(J.bhh + HH + u0);
  const floatx4 bhn = *(const floatx4*)(J.bhh + 2*HH + u0);
  floatx4 hreg = (floatx4)0.f;
  for (int i = tid; i < BB*HH; i += 512){   // zero both hi/lo buffers (2048 ushorts each pair slot)
    ((unsigned*)hhi)[i] = 0u;
    ((unsigned*)hlo)[i] = 0u;
  }
  __syncthreads();

  for (int c0=0; c0<TT; c0+=GCH){
    // stage GCH xg rows for all batches: GCH*8*384 floats = 1536 float4; 3 per thread
    #pragma unroll
    for (int it=0; it<3; it++){
      const int idx = it*512 + tid;
      const int si = idx/768, rem = idx - si*768;
      const int bb = rem/96, c4 = rem - bb*96;
      const int tt = J.rev ? (TT-1-(c0+si)) : (c0+si);
      *(floatx4*)&xgt[si][bb][c4*4] = *(const floatx4*)(J.xg + ((long)bb*TT + tt)*G3 + c4*4);
    }
    __syncthreads();
    #pragma unroll
    for (int si=0; si<GCH; si++){
      const int s = c0 + si;
      const int buf = s & 1;
      floatx4 accr=(floatx4)0.f, accz=(floatx4)0.f, accn=(floatx4)0.f;
      #pragma unroll
      for (int kc=0; kc<4; kc++){
        BF Bh, Bl;
        Bh.d = *(const uint4*)&hhi[buf][b][kc*32 + q*8];
        Bl.d = *(const uint4*)&hlo[buf][b][kc*32 + q*8];
        accr = __builtin_amdgcn_mfma_f32_16x16x32_bf16(Ah[0][kc].v, Bh.v, accr, 0,0,0);
        accz = __builtin_amdgcn_mfma_f32_16x16x32_bf16(Ah[1][kc].v, Bh.v, accz, 0,0,0);
        accn = __builtin_amdgcn_mfma_f32_16x16x32_bf16(Ah[2][kc].v, Bh.v, accn, 0,0,0);
        accr = __builtin_amdgcn_mfma_f32_16x16x32_bf16(Ah[0][kc].v, Bl.v, accr, 0,0,0);
        accz = __builtin_amdgcn_mfma_f32_16x16x32_bf16(Ah[1][kc].v, Bl.v, accz, 0,0,0);
        accn = __builtin_amdgcn_mfma_f32_16x16x32_bf16(Ah[2][kc].v, Bl.v, accn, 0,0,0);
        accr = __builtin_amdgcn_mfma_f32_16x16x32_bf16(Al[0][kc].v, Bh.v, accr, 0,0,0);
        accz = __builtin_amdgcn_mfma_f32_16x16x32_bf16(Al[1][kc].v, Bh.v, accz, 0,0,0);
        accn = __builtin_amdgcn_mfma_f32_16x16x32_bf16(Al[2][kc].v, Bh.v, accn, 0,0,0);
      }
      if (act){
        const float* xb = &xgt[si][b][0];
        const floatx4 cxr = *(const floatx4*)(xb + u0);
        const floatx4 cxz = *(const floatx4*)(xb + HH + u0);
        const floatx4 cxn = *(const floatx4*)(xb + 2*HH + u0);
        floatx4 hnew;
        union { unsigned short u[4]; uint2 d; } h4, l4;
        #pragma unroll
        for (int r=0; r<4; r++){
          const float gr = fsigmoid(cxr[r] + accr[r] + bhr[r]);
          const float gz = fsigmoid(cxz[r] + accz[r] + bhz[r]);
          const float gn = ftanh  (cxn[r] + gr*(accn[r] + bhn[r]));
          hnew[r] = (1.f-gz)*gn + gz*hreg[r];
          split2(hnew[r], h4.u[r], l4.u[r]);
        }
        hreg = hnew;
        const int nbuf = 1 - buf;
        *(uint2*)&hhi[nbuf][b][u0] = h4.d;
        *(uint2*)&hlo[nbuf][b][u0] = l4.d;
        *(floatx4*)&hbuf[si][b][u0] = hnew;
      }
      __syncthreads();
    }
    // flush GCH rows: GCH*8*128 floats = 512 float4; 1 per thread
    {
      const int idx = tid;
      const int si = idx >> 8, rem = idx & 255;
      const int bb = rem >> 5, c4 = rem & 31;
      const int tt = J.rev ? (TT-1-(c0+si)) : (c0+si);
      *(floatx4*)(J.out + ((long)bb*TT + tt)*D2 + J.ocol + c4*4) = *(const floatx4*)&hbuf[si][bb][c4*4];
    }
  }
}

// ---------------- block softmax over 160 values (256 threads) ----------------
__device__ inline float block_softmax160(float s, int tid, float* red){
  float m = s;
  #pragma unroll
  for (int o=32;o>0;o>>=1) m = fmaxf(m, __shfl_xor(m,o));
  if ((tid&63)==0) red[tid>>6] = m;
  __syncthreads();
  m = fmaxf(fmaxf(red[0],red[1]), fmaxf(red[2],red[3]));
  const float p = (tid<TT) ? __expf(s-m) : 0.f;
  float t = p;
  #pragma unroll
  for (int o=32;o>0;o>>=1) t += __shfl_xor(t,o);
  if ((tid&63)==0) red[4+(tid>>6)] = t;
  __syncthreads();
  const float sum = red[4]+red[5]+red[6]+red[7];
  return p / sum;
}

// ---------------- block softmax over 160 values (512 threads) ----------------
__device__ inline float block_softmax160_512(float s, int tid, float* red){
  float m = s;
  #pragma unroll
  for (int o=32;o>0;o>>=1) m = fmaxf(m, __shfl_xor(m,o));
  if ((tid&63)==0) red[tid>>6] = m;
  __syncthreads();
  m = red[0];
  #pragma unroll
  for (int i=1;i<8;i++) m = fmaxf(m, red[i]);
  const float p = (tid<TT) ? __expf(s-m) : 0.f;
  float t = p;
  #pragma unroll
  for (int o=32;o>0;o>>=1) t += __shfl_xor(t,o);
  if ((tid&63)==0) red[8+(tid>>6)] = t;
  __syncthreads();
  float sum = red[8];
  #pragma unroll
  for (int i=1;i<8;i++) sum += red[8+i];
  return p / sum;
}

// ---------------- pairwise product attention (dot & self) via MFMA + LDS pipeline ----------------
struct PairJob { const unsigned short* Phi; const unsigned short* Plo;
                 const float* Q; const float* W; const float* V; float* a_out; };

__global__ __launch_bounds__(512) void k_pairattn(PairJob j0, PairJob j1){
  const PairJob J = blockIdx.z ? j1 : j0;
  const int b = blockIdx.y, c = blockIdx.x;
  const int tid = threadIdx.x;
  const int lane = tid & 63, w = tid >> 6;
  const int l15 = lane & 15, q = lane >> 4;
  __shared__ unsigned short Pb[2*2*160*PSTR];
  __shared__ float Qs[D2];
  __shared__ float sc_sh[TT];
  __shared__ float red[16];
  if (tid < D2) Qs[tid] = J.Q[((long)b*TT + c)*D2 + tid];
  if (tid < TT) sc_sh[tid] = 0.f;
  const long pbase = (long)b*TT*D2;

  int s_hl[5], s_t[5], s_d4[5];
  #pragma unroll
  for (int r=0;r<5;r++){
    const int idx = tid + r*512;
    const int hl = (idx >= 1280) ? 1 : 0;
    const int e4 = idx - hl*1280;
    s_hl[r] = hl; s_t[r] = e4 >> 3; s_d4[r] = e4 & 7;
  }
  uint2 stg[5];
  #pragma unroll
  for (int r=0;r<5;r++){
    const unsigned short* src = (s_hl[r] ? J.Plo : J.Phi) + pbase + (long)s_t[r]*D2 + s_d4[r]*4;
    stg[r] = *(const uint2*)src;
  }
  const float* Wbase = J.W + (long)(w*16 + l15)*D2;
  floatx4 wv0 = *(const floatx4*)(Wbase + q*8);
  floatx4 wv1 = *(const floatx4*)(Wbase + q*8 + 4);
  #pragma unroll
  for (int r=0;r<5;r++)
    *(uint2*)&Pb[((0*2 + s_hl[r])*160 + s_t[r])*PSTR + s_d4[r]*4] = stg[r];
  __syncthreads();

  floatx4 acc[10];
  #pragma unroll
  for (int nt=0;nt<10;nt++) acc[nt] = (floatx4)0.f;

  for (int kc=0; kc<8; kc++){
    const floatx4 wc0 = wv0, wc1 = wv1;
    if (kc < 7){
      wv0 = *(const floatx4*)(Wbase + (kc+1)*32 + q*8);
      wv1 = *(const floatx4*)(Wbase + (kc+1)*32 + q*8 + 4);
      #pragma unroll
      for (int r=0;r<5;r++){
        const unsigned short* src = (s_hl[r] ? J.Plo : J.Phi) + pbase + (long)s_t[r]*D2 + (kc+1)*32 + s_d4[r]*4;
        stg[r] = *(const uint2*)src;
      }
    }
    const int d0 = kc*32 + q*8;
    const floatx4 q0 = *(const floatx4*)&Qs[d0];
    const floatx4 q1 = *(const floatx4*)&Qs[d0+4];
    union { bf16x8 v; unsigned short u[8]; } ah, al;
    #pragma unroll
    for (int j=0;j<4;j++){
      split2(wc0[j]*q0[j], ah.u[j],   al.u[j]);
      split2(wc1[j]*q1[j], ah.u[4+j], al.u[4+j]);
    }
    const int buf = kc & 1;
    #pragma unroll
    for (int nt=0;nt<10;nt++){
      const int t = nt*16 + l15;
      union { bf16x8 v; } bh, bl;
      bh.v = *(const bf16x8*)&Pb[((buf*2+0)*160 + t)*PSTR + q*8];
      bl.v = *(const bf16x8*)&Pb[((buf*2+1)*160 + t)*PSTR + q*8];
      acc[nt] = __builtin_amdgcn_mfma_f32_16x16x32_bf16(ah.v, bh.v, acc[nt], 0,0,0);
      acc[nt] = __builtin_amdgcn_mfma_f32_16x16x32_bf16(ah.v, bl.v, acc[nt], 0,0,0);
      acc[nt] = __builtin_amdgcn_mfma_f32_16x16x32_bf16(al.v, bh.v, acc[nt], 0,0,0);
    }
    if (kc < 7){
      const int nbuf = 1 - buf;
      #pragma unroll
      for (int r=0;r<5;r++)
        *(uint2*)&Pb[((nbuf*2 + s_hl[r])*160 + s_t[r])*PSTR + s_d4[r]*4] = stg[r];
      __syncthreads();
    }
  }

  float vreg[4];
  #pragma unroll
  for (int r=0;r<4;r++) vreg[r] = J.V[w*16 + q*4 + r];
  #pragma unroll
  for (int nt=0;nt<10;nt++){
    float pp = 0.f;
    #pragma unroll
    for (int r=0;r<4;r++) pp += vreg[r]*ftanh(acc[nt][r]);
    pp += __shfl_xor(pp,16);
    pp += __shfl_xor(pp,32);
    if (q==0) atomicAdd(&sc_sh[nt*16 + l15], pp);
  }
  __syncthreads();
  const float s = (tid<TT)? sc_sh[tid] : -INFINITY;
  const float a = block_softmax160_512(s, tid, red);
  if (tid < TT) J.a_out[((long)b*TT + c)*TT + tid] = a;
}

// ---------------- additive attentions (concat / minus) ----------------
struct AddJob { const float* up; const float* uc; const float* V; float sgn; float* a_out; };

__global__ __launch_bounds__(256) void k_addattn(AddJob j0, AddJob j1){
  const AddJob J = blockIdx.z ? j1 : j0;
  const int b = blockIdx.y, c = blockIdx.x, tid = threadIdx.x;
  __shared__ float ucc[HH];
  __shared__ float vv[HH];
  __shared__ float red[8];
  if (tid < HH){
    ucc[tid] = J.sgn * J.uc[((long)b*TT + c)*HH + tid];
    vv[tid] = J.V[tid];
  }
  __syncthreads();
  float s = -INFINITY;
  if (tid < TT){
    const float* ur = J.up + ((long)b*TT + tid)*HH;
    float a0 = 0.f;
    #pragma unroll 4
    for (int k=0;k<HH;k++) a0 += vv[k]*ftanh(ur[k]+ucc[k]);
    s = a0;
  }
  const float a = block_softmax160(s, tid, red);
  if (tid < TT) J.a_out[((long)b*TT + c)*TT + tid] = a;
}

// ---------------- bilinear attention ----------------
__global__ __launch_bounds__(256) void k_bilattn(const float* hc, const float* hpWb, float* a_out){
  const int b = blockIdx.y, c = blockIdx.x, tid = threadIdx.x;
  __shared__ float hcc[D2];
  __shared__ float red[8];
  if (tid < D2) hcc[tid] = hc[((long)b*TT + c)*D2 + tid];
  __syncthreads();
  float s = -INFINITY;
  if (tid < TT){
    const float* pr = hpWb + ((long)b*TT + tid)*D2;
    float a0 = 0.f;
    #pragma unroll 4
    for (int k=0;k<D2;k++) a0 += hcc[k]*pr[k];
    s = a0;
  }
  const float a = block_softmax160(s, tid, red);
  if (tid < TT) a_out[((long)b*TT + c)*TT + tid] = a;
}

// ---------------- rep build ----------------
__global__ __launch_bounds__(256) void k_rep(const float* hp, const float* hc,
    const float* acat, const float* abil, const float* adot, const float* amin, const float* aself,
    float* aggin){
  const int b = blockIdx.y, c = blockIdx.x, tid = threadIdx.x;
  __shared__ float a5[5][TT];
  {
    const long base = ((long)b*TT + c)*TT;
    for (int i=tid;i<5*TT;i+=256){
      const int which = i/TT, t = i - which*TT;
      const float* p = which==0? acat : which==1? abil : which==2? adot : which==3? amin : aself;
      a5[which][t] = p[base + t];
    }
  }
  __syncthreads();
  const float* hpb = hp + (long)b*TT*D2 + tid;
  const float* hcb = hc + (long)b*TT*D2 + tid;
  float r0=0.f,r1=0.f,r2=0.f,r3=0.f,r4=0.f;
  for (int t=0;t<TT;t++){
    const float vp = hpb[(long)t*D2];
    const float vc = hcb[(long)t*D2];
    r0 += a5[0][t]*vp;
    r1 += a5[1][t]*vp;
    r2 += a5[2][t]*vp;
    r3 += a5[3][t]*vp;
    r4 += a5[4][t]*vc;
  }
  float* o = aggin + ((long)b*TT + c)*(6*D2);
  o[tid]        = hc[((long)b*TT + c)*D2 + tid];
  o[D2 + tid]   = r4;
  o[2*D2 + tid] = r0;
  o[3*D2 + tid] = r2;
  o[4*D2 + tid] = r1;
  o[5*D2 + tid] = r3;
}

// ---------------- tail1 ----------------
__global__ __launch_bounds__(256) void k_tail1(const float* upP, const float* Vp,
    const float* hp, float* rp){
  const int b = blockIdx.x, tid = threadIdx.x;
  __shared__ float vv[HH];
  __shared__ float ap_sh[TT];
  __shared__ float red[8];
  if (tid<HH) vv[tid] = Vp[tid];
  __syncthreads();
  float s = -INFINITY;
  if (tid<TT){
    const float* ur = upP + ((long)b*TT + tid)*HH;
    float a0=0.f;
    #pragma unroll 4
    for (int k=0;k<HH;k++) a0 += vv[k]*ftanh(ur[k]);
    s = a0;
  }
  const float a = block_softmax160(s, tid, red);
  if (tid<TT) ap_sh[tid] = a;
  __syncthreads();
  float acc = 0.f;
  const float* hpb = hp + (long)b*TT*D2 + tid;
  for (int t=0;t<TT;t++) acc += ap_sh[t]*hpb[(long)t*D2];
  rp[b*D2 + tid] = acc;
}

// ---------------- tail2 ----------------
__global__ __launch_bounds__(256) void k_tail2(const float* aggW1, const float* agg, const float* rp,
    const float* W2, const float* Vv, const float* Wout, const float* bout,
    float* out){
  const int b = blockIdx.x, tid = threadIdx.x;
  __shared__ float rpw[HH];
  __shared__ float ac_sh[TT];
  __shared__ float rc_sh[D2];
  __shared__ float red[8];
  if (tid < HH){
    float a0=0.f;
    const float* wr2 = W2 + (long)tid*D2;
    const float* rr = rp + b*D2;
    for (int d=0; d<D2; d++) a0 += wr2[d]*rr[d];
    rpw[tid] = a0;
  }
  __syncthreads();
  float s = -INFINITY;
  if (tid < TT){
    const float* ar = aggW1 + ((long)b*TT + tid)*HH;
    float a0=0.f;
    for (int k=0;k<HH;k++) a0 += Vv[k]*(ar[k] + rpw[k]);
    s = a0;
  }
  const float a = block_softmax160(s, tid, red);
  if (tid < TT) ac_sh[tid] = a;
  __syncthreads();
  float rc=0.f;
  const float* ab = agg + (long)b*TT*D2 + tid;
  for (int t=0;t<TT;t++) rc += ac_sh[t]*ab[(long)t*D2];
  rc_sh[tid] = rc;
  __syncthreads();
  if (tid < 2){
    float o = bout[tid];
    const float* wr = Wout + (long)tid*D2;
    for (int d=0; d<D2; d++) o += wr[d]*rc_sh[d];
    out[b*2 + tid] = o;
  }
}

extern "C" void kernel_launch(void* const* d_in, const int* in_sizes, int n_in,
                              void* d_out, int out_size, void* d_ws, size_t ws_size,
                              hipStream_t stream){
  (void)in_sizes; (void)n_in; (void)out_size; (void)ws_size;
  const int* ta = (const int*)d_in[0];
  const int* tb = (const int*)d_in[1];
  const float* emb = (const float*)d_in[2];
  #define F32(i) ((const float*)d_in[i])

  float* ws = (float*)d_ws;
  float* ep    = ws;                 // 8*160*300
  float* ec    = ep    + 384000;
  float* xg_pf = ec    + 384000;     // 8*160*384 each; reused by agg stage later
  float* xg_pb = xg_pf + 491520;
  float* xg_cf = xg_pb + 491520;
  float* xg_cb = xg_cf + 491520;
  float* hp    = xg_cb + 491520;     // 8*160*256
  float* hc    = hp    + 327680;
  float* up1   = hc    + 327680;     // 8*160*128 each
  float* uc2   = up1   + 163840;
  float* ump   = uc2   + 163840;
  float* umc   = ump   + 163840;
  float* upP   = umc   + 163840;
  float* hpWb  = upP   + 163840;     // 8*160*256
  float* acat  = hpWb  + 327680;     // 8*160*160 each
  float* abil  = acat  + 204800;
  float* adot  = abil  + 204800;
  float* amin  = adot  + 204800;
  float* aself = amin  + 204800;
  float* aggin = aself + 204800;     // 8*160*1536
  float* rp    = aggin + 1966080;    // 8*256
  unsigned short* hp_hi = (unsigned short*)(rp + 2048);   // 327680 u16 each
  unsigned short* hp_lo = hp_hi + 327680;
  unsigned short* hc_hi = hp_lo + 327680;
  unsigned short* hc_lo = hc_hi + 327680;
  // pre-split weight region (ushort), padded rows
  unsigned short* wsp = hc_lo + 327680;
  unsigned short* w3h  = wsp;             unsigned short* w3l  = w3h  + 122880;  // 384x320
  unsigned short* w7h  = w3l  + 122880;   unsigned short* w7l  = w7h  + 122880;
  unsigned short* w11h = w7l  + 122880;   unsigned short* w11l = w11h + 122880;
  unsigned short* w15h = w11l + 122880;   unsigned short* w15l = w15h + 122880;
  unsigned short* w27h = w15l + 122880;   unsigned short* w27l = w27h + 32768;   // 128x256
  unsigned short* w28h = w27l + 32768;    unsigned short* w28l = w28h + 32768;
  unsigned short* w33h = w28l + 32768;    unsigned short* w33l = w33h + 32768;
  unsigned short* w37h = w33l + 32768;    unsigned short* w37l = w37h + 32768;
  unsigned short* w30h = w37l + 32768;    unsigned short* w30l = w30h + 65536;   // 256x256
  unsigned short* w19h = w30l + 65536;    unsigned short* w19l = w19h + 589824;  // 384x1536
  unsigned short* w23h = w19l + 589824;   unsigned short* w23l = w23h + 589824;
  unsigned short* w39h = w23l + 589824;   unsigned short* w39l = w39h + 32768;   // 128x256
  // dead-buffer reuse for the agg stage:
  float* xg_af = xg_pf;
  float* xg_ab = xg_pb;
  float* agg   = xg_cf;
  float* aggW1 = xg_cb;

  // 1) embedding gather + weight pre-split
  k_embed<<<dim3(3000), dim3(256), 0, stream>>>(ta, tb, emb, ep, ec);
  SplitJobs sj = {};
  sj.j[0]  = {F32(3),  w3h,  w3l,  122880, 300, 320};
  sj.j[1]  = {F32(7),  w7h,  w7l,  122880, 300, 320};
  sj.j[2]  = {F32(11), w11h, w11l, 122880, 300, 320};
  sj.j[3]  = {F32(15), w15h, w15l, 122880, 300, 320};
  sj.j[4]  = {F32(27), w27h, w27l, 32768,  256, 256};
  sj.j[5]  = {F32(28), w28h, w28l, 32768,  256, 256};
  sj.j[6]  = {F32(33), w33h, w33l, 32768,  256, 256};
  sj.j[7]  = {F32(37), w37h, w37l, 32768,  256, 256};
  sj.j[8]  = {F32(30), w30h, w30l, 65536,  256, 256};
  sj.j[9]  = {F32(19), w19h, w19l, 589824, 1536, 1536};
  sj.j[10] = {F32(23), w23h, w23l, 589824, 1536, 1536};
  sj.j[11] = {F32(39), w39h, w39l, 32768,  256, 256};
  k_splitw<<<dim3(2304,1,12), dim3(256), 0, stream>>>(sj);

  // 2) xg = x @ Wih^T + bih for p/c  (M=1280, N=384, K=300, Kp=320)
  GemmSJobs ja = {};
  ja.j[0] = {ep, w3h,  w3l,  F32(5),  xg_pf, 384, 300, 320};
  ja.j[1] = {ep, w7h,  w7l,  F32(9),  xg_pb, 384, 300, 320};
  ja.j[2] = {ec, w11h, w11l, F32(13), xg_cf, 384, 300, 320};
  ja.j[3] = {ec, w15h, w15l, F32(17), xg_cb, 384, 300, 320};
  k_gemmS<<<dim3(6,20,4), dim3(256), 0, stream>>>(ja);

  // 3) p/c GRU scans (batch-packed MFMA v5; one block per direction)
  GruJobs gj = {};
  gj.j[0] = {xg_pf, F32(4),  F32(6),  hp, 0,   0};
  gj.j[1] = {xg_pb, F32(8),  F32(10), hp, 128, 1};
  gj.j[2] = {xg_cf, F32(12), F32(14), hc, 0,   0};
  gj.j[3] = {xg_cb, F32(16), F32(18), hc, 128, 1};
  k_gru<<<dim3(4), dim3(512), 0, stream>>>(gj);

  // 3b) hi/lo split of hp & hc for pairattn B-operands
  k_splitarr<<<dim3(1280), dim3(256), 0, stream>>>(hp, hc, 327680, hp_hi, hp_lo, hc_hi, hc_lo);

  // 4) projection GEMMs (K=256)
  GemmSJobs jb = {};
  jb.j[0] = {hp, w27h, w27l, nullptr, up1,  128, 256, 256};
  jb.j[1] = {hc, w28h, w28l, nullptr, uc2,  128, 256, 256};
  jb.j[2] = {hp, w33h, w33l, nullptr, ump,  128, 256, 256};
  jb.j[3] = {hc, w33h, w33l, nullptr, umc,  128, 256, 256};
  jb.j[4] = {hp, w37h, w37l, nullptr, upP,  128, 256, 256};
  jb.j[5] = {hp, w30h, w30l, nullptr, hpWb, 256, 256, 256};
  k_gemmS<<<dim3(4,20,6), dim3(256), 0, stream>>>(jb);

  // 5) dot & self attentions (MFMA, LDS double-buffered pipeline)
  PairJob pd  = {hp_hi, hp_lo, hc, F32(31), F32(32), adot};
  PairJob psf = {hc_hi, hc_lo, hc, F32(35), F32(36), aself};
  k_pairattn<<<dim3(160,8,2), dim3(512), 0, stream>>>(pd, psf);

  // 6) concat & minus attentions
  AddJob ac_ = {up1, uc2, F32(29),  1.f, acat};
  AddJob am_ = {ump, umc, F32(34), -1.f, amin};
  k_addattn<<<dim3(160,8,2), dim3(256), 0, stream>>>(ac_, am_);

  // 7) bilinear attention
  k_bilattn<<<dim3(160,8), dim3(256), 0, stream>>>(hc, hpWb, abil);

  // 8) ap/rp pooling
  k_tail1<<<dim3(8), dim3(256), 0, stream>>>(upP, F32(38), hp, rp);

  // 9) weighted reps -> agg_in
  k_rep<<<dim3(160,8), dim3(256), 0, stream>>>(hp, hc, acat, abil, adot, amin, aself, aggin);

  // 10) agg xg GEMMs (M=1280, N=384, K=1536)
  GemmSJobs jc = {};
  jc.j[0] = {aggin, w19h, w19l, F32(21), xg_af, 384, 1536, 1536};
  jc.j[1] = {aggin, w23h, w23l, F32(25), xg_ab, 384, 1536, 1536};
  k_gemmS<<<dim3(6,20,2), dim3(256), 0, stream>>>(jc);

  // 11) agg GRU scans (batch-packed MFMA v5)
  GruJobs gja = {};
  gja.j[0] = {xg_af, F32(20), F32(22), agg, 0,   0};
  gja.j[1] = {xg_ab, F32(24), F32(26), agg, 128, 1};
  k_gru<<<dim3(2), dim3(512), 0, stream>>>(gja);

  // 12) agg @ W1^T (N=128, K=256)
  GemmSJobs jd = {};
  jd.j[0] = {agg, w39h, w39l, nullptr, aggW1, 128, 256, 256};
  k_gemmS<<<dim3(2,20,1), dim3(256), 0, stream>>>(jd);

  // 13) final scores + output
  k_tail2<<<dim3(8), dim3(256), 0, stream>>>(aggW1, agg, rp, F32(40), F32(41), F32(42), F32(43),
                                             (float*)d_out);
  #undef F32
}

// Round 12
// 838.184 us; speedup vs baseline: 1.5305x; 1.5305x over previous
//
#include <hip/hip_runtime.h>

#define BB 8
#define TT 160
#define EE 300
#define HH 128
#define D2 256
#define G3 384
#define PSTR 40   // padded LDS row stride (shorts) for P tiles

typedef __attribute__((ext_vector_type(8))) short bf16x8;
typedef __attribute__((ext_vector_type(4))) float floatx4;

__device__ inline float fsigmoid(float x){ return 1.f/(1.f+__expf(-x)); }
__device__ inline float ftanh(float x){ return 2.f*fsigmoid(2.f*x) - 1.f; }

// truncation split: x ~= hi + lo, each bf16; combined rel err <= ~2^-16
__device__ inline void split2(float x, unsigned short& hi, unsigned short& lo){
  unsigned ux = __float_as_uint(x);
  hi = (unsigned short)(ux>>16);
  float r = x - __uint_as_float(ux & 0xFFFF0000u);
  lo = (unsigned short)(__float_as_uint(r)>>16);
}

// ---------------- embedding gather ----------------
__global__ __launch_bounds__(256) void k_embed(const int* ta, const int* tb,
    const float* emb, float* ep, float* ec){
  const int idx = blockIdx.x*256 + threadIdx.x;
  const int per = BB*TT*EE;
  if (idx < per){
    const int e = idx % EE, bt = idx / EE;
    ep[idx] = emb[(long)ta[bt]*EE + e];
  } else {
    const int j = idx - per;
    const int e = j % EE, bt = j / EE;
    ec[j] = emb[(long)tb[bt]*EE + e];
  }
}

// ---------------- hi/lo bf16 split of hp & hc ----------------
__global__ __launch_bounds__(256) void k_splitarr(const float* a, const float* b, int n,
    unsigned short* ahi, unsigned short* alo, unsigned short* bhi, unsigned short* blo){
  const int idx = blockIdx.x*256 + threadIdx.x;
  if (idx < n){
    split2(a[idx], ahi[idx], alo[idx]);
    split2(b[idx], bhi[idx], blo[idx]);
  }
}

// ---------------- weight pre-split: W[N x K](f32) -> hi/lo bf16 [N x Kp], zero-padded ----------------
struct SplitJob { const float* W; unsigned short* hi; unsigned short* lo; int n; int K; int Kp; };
struct SplitJobs { SplitJob j[12]; };

__global__ __launch_bounds__(256) void k_splitw(SplitJobs jobs){
  const SplitJob J = jobs.j[blockIdx.z];
  const int idx = blockIdx.x*256 + threadIdx.x;
  if (idx >= J.n) return;
  const int row = idx / J.Kp, k = idx - row*J.Kp;
  const float v = (k < J.K) ? J.W[(long)row*J.K + k] : 0.f;
  split2(v, J.hi[idx], J.lo[idx]);
}

// ---------------- MFMA GEMM with pre-split W: C = A(f32) @ W^T + bias ----------------
struct GemmSJob {
  const float* A; const unsigned short* Whi; const unsigned short* Wlo; const float* bias;
  float* C; int N; int K; int Kp;
};
struct GemmSJobs { GemmSJob j[6]; };

__global__ __launch_bounds__(256) void k_gemmS(GemmSJobs jobs){
  const GemmSJob J = jobs.j[blockIdx.z];
  const int tid = threadIdx.x;
  const int lane = tid & 63, w = tid >> 6;
  const int l15 = lane & 15, q = lane >> 4;
  const int n0 = blockIdx.x * 64;
  if (n0 >= J.N) return;
  const int K = J.K, Kp = J.Kp;
  const long mrow = blockIdx.y*64 + w*16 + l15;
  const float* Arow = J.A + mrow*K;
  floatx4 acc[4];
  #pragma unroll
  for (int t=0;t<4;t++) acc[t] = (floatx4)0.f;
  const int nch = (K+31)>>5;
  for (int kc=0; kc<nch; kc++){
    const int k0 = kc<<5;
    const int kb = k0 + q*8;
    float av[8];
    if (k0+32 <= K){
      const floatx4 a0 = *(const floatx4*)(Arow+kb);
      const floatx4 a1 = *(const floatx4*)(Arow+kb+4);
      av[0]=a0[0];av[1]=a0[1];av[2]=a0[2];av[3]=a0[3];
      av[4]=a1[0];av[5]=a1[1];av[6]=a1[2];av[7]=a1[3];
    } else {
      #pragma unroll
      for (int j=0;j<8;j++){ const int k=kb+j; av[j] = (k<K)? Arow[k] : 0.f; }
    }
    union { bf16x8 v; unsigned short u[8]; } ahi, alo;
    #pragma unroll
    for (int j=0;j<8;j++) split2(av[j], ahi.u[j], alo.u[j]);
    #pragma unroll
    for (int t=0;t<4;t++){
      const int n = n0 + t*16 + l15;
      const long wo = (long)n*Kp + kb;
      union { bf16x8 v; uint4 d; } whi, wlo;
      whi.d = *(const uint4*)(J.Whi + wo);
      wlo.d = *(const uint4*)(J.Wlo + wo);
      acc[t] = __builtin_amdgcn_mfma_f32_16x16x32_bf16(ahi.v, whi.v, acc[t], 0,0,0);
      acc[t] = __builtin_amdgcn_mfma_f32_16x16x32_bf16(ahi.v, wlo.v, acc[t], 0,0,0);
      acc[t] = __builtin_amdgcn_mfma_f32_16x16x32_bf16(alo.v, whi.v, acc[t], 0,0,0);
    }
  }
  const long rbase = blockIdx.y*64 + w*16 + q*4;
  #pragma unroll
  for (int t=0;t<4;t++){
    const int n = n0 + t*16 + l15;
    const float bv = J.bias ? J.bias[n] : 0.f;
    #pragma unroll
    for (int r=0;r<4;r++)
      J.C[(rbase+r)*(long)J.N + n] = acc[t][r] + bv;
  }
}

// ---------------- GRU scan v4 (reverted r10 best): 512 threads, 4 threads per h-unit ----------------
struct GruJob { const float* xg; const float* Whh; const float* bhh; float* out; int ocol; int rev; };
struct GruJobs { GruJob j[4]; };

__global__ __launch_bounds__(512,1) void k_gru(GruJobs jobs){
  const GruJob J = jobs.j[blockIdx.y];
  const int bi = blockIdx.x;
  const int tid = threadIdx.x;
  const int j = tid >> 2, p = tid & 3;
  __shared__ float xgt[16][G3];    // staged xg rows (storage-step order)
  __shared__ float hbuf[16][HH];   // output buffer
  __shared__ float hcur[2][HH];    // double-buffered h
  float wr[32], wz[32], wn[32];
  {
    const float* r0 = J.Whh + (long)j*HH + p*32;
    const float* z0 = J.Whh + (long)(HH+j)*HH + p*32;
    const float* n0 = J.Whh + (long)(2*HH+j)*HH + p*32;
    #pragma unroll
    for (int k=0;k<32;k+=4){
      *(floatx4*)&wr[k] = *(const floatx4*)(r0+k);
      *(floatx4*)&wz[k] = *(const floatx4*)(z0+k);
      *(floatx4*)&wn[k] = *(const floatx4*)(n0+k);
    }
  }
  float bhr=0.f,bhz=0.f,bhn=0.f;
  if (p==0){ bhr = J.bhh[j]; bhz = J.bhh[HH+j]; bhn = J.bhh[2*HH+j]; }
  if (tid < 256) ((float*)hcur)[tid] = 0.f;
  float hreg = 0.f;
  __syncthreads();

  for (int s0=0; s0<TT; s0+=16){
    #pragma unroll
    for (int r=0;r<3;r++){
      const int i = r*512 + tid;
      const int row = i/96, c4 = i - row*96;
      const int tt = J.rev ? (TT-1-(s0+row)) : (s0+row);
      *(floatx4*)&xgt[row][c4*4] = *(const floatx4*)(J.xg + ((long)bi*TT + tt)*G3 + c4*4);
    }
    __syncthreads();
    for (int si=0; si<16; si++){
      const int s = s0 + si;
      const int buf = s & 1;
      float cxr=0.f,cxz=0.f,cxn=0.f;
      if (p==0){ cxr = xgt[si][j]; cxz = xgt[si][HH+j]; cxn = xgt[si][2*HH+j]; }
      float ar=0.f, az=0.f, an=0.f;
      #pragma unroll
      for (int k=0;k<32;k+=4){
        const floatx4 h4 = *(const floatx4*)&hcur[buf][p*32+k];
        ar += wr[k]*h4[0] + wr[k+1]*h4[1] + wr[k+2]*h4[2] + wr[k+3]*h4[3];
        az += wz[k]*h4[0] + wz[k+1]*h4[1] + wz[k+2]*h4[2] + wz[k+3]*h4[3];
        an += wn[k]*h4[0] + wn[k+1]*h4[1] + wn[k+2]*h4[2] + wn[k+3]*h4[3];
      }
      ar += __shfl_xor(ar,1); ar += __shfl_xor(ar,2);
      az += __shfl_xor(az,1); az += __shfl_xor(az,2);
      an += __shfl_xor(an,1); an += __shfl_xor(an,2);
      if (p==0){
        const float gr = fsigmoid(cxr + ar + bhr);
        const float gz = fsigmoid(cxz + az + bhz);
        const float gn = ftanh  (cxn + gr*(an + bhn));
        const float h = (1.f-gz)*gn + gz*hreg;
        hreg = h;
        hcur[1-buf][j] = h;
        hbuf[si][j] = h;
      }
      __syncthreads();
    }
    {
      const int row = tid >> 5, c4 = tid & 31;
      const int tt = J.rev ? (TT-1-(s0+row)) : (s0+row);
      *(floatx4*)(J.out + ((long)bi*TT + tt)*D2 + J.ocol + c4*4) = *(const floatx4*)&hbuf[row][c4*4];
    }
  }
}

// ---------------- block softmax over 160 values (256 threads) ----------------
__device__ inline float block_softmax160(float s, int tid, float* red){
  float m = s;
  #pragma unroll
  for (int o=32;o>0;o>>=1) m = fmaxf(m, __shfl_xor(m,o));
  if ((tid&63)==0) red[tid>>6] = m;
  __syncthreads();
  m = fmaxf(fmaxf(red[0],red[1]), fmaxf(red[2],red[3]));
  const float p = (tid<TT) ? __expf(s-m) : 0.f;
  float t = p;
  #pragma unroll
  for (int o=32;o>0;o>>=1) t += __shfl_xor(t,o);
  if ((tid&63)==0) red[4+(tid>>6)] = t;
  __syncthreads();
  const float sum = red[4]+red[5]+red[6]+red[7];
  return p / sum;
}

// ---------------- block softmax over 160 values (512 threads) ----------------
__device__ inline float block_softmax160_512(float s, int tid, float* red){
  float m = s;
  #pragma unroll
  for (int o=32;o>0;o>>=1) m = fmaxf(m, __shfl_xor(m,o));
  if ((tid&63)==0) red[tid>>6] = m;
  __syncthreads();
  m = red[0];
  #pragma unroll
  for (int i=1;i<8;i++) m = fmaxf(m, red[i]);
  const float p = (tid<TT) ? __expf(s-m) : 0.f;
  float t = p;
  #pragma unroll
  for (int o=32;o>0;o>>=1) t += __shfl_xor(t,o);
  if ((tid&63)==0) red[8+(tid>>6)] = t;
  __syncthreads();
  float sum = red[8];
  #pragma unroll
  for (int i=1;i<8;i++) sum += red[8+i];
  return p / sum;
}

// ---------------- pairwise product attention (dot & self) via MFMA + LDS pipeline ----------------
struct PairJob { const unsigned short* Phi; const unsigned short* Plo;
                 const float* Q; const float* W; const float* V; float* a_out; };

__global__ __launch_bounds__(512) void k_pairattn(PairJob j0, PairJob j1){
  const PairJob J = blockIdx.z ? j1 : j0;
  const int b = blockIdx.y, c = blockIdx.x;
  const int tid = threadIdx.x;
  const int lane = tid & 63, w = tid >> 6;
  const int l15 = lane & 15, q = lane >> 4;
  __shared__ unsigned short Pb[2*2*160*PSTR];
  __shared__ float Qs[D2];
  __shared__ float sc_sh[TT];
  __shared__ float red[16];
  if (tid < D2) Qs[tid] = J.Q[((long)b*TT + c)*D2 + tid];
  if (tid < TT) sc_sh[tid] = 0.f;
  const long pbase = (long)b*TT*D2;

  int s_hl[5], s_t[5], s_d4[5];
  #pragma unroll
  for (int r=0;r<5;r++){
    const int idx = tid + r*512;
    const int hl = (idx >= 1280) ? 1 : 0;
    const int e4 = idx - hl*1280;
    s_hl[r] = hl; s_t[r] = e4 >> 3; s_d4[r] = e4 & 7;
  }
  uint2 stg[5];
  #pragma unroll
  for (int r=0;r<5;r++){
    const unsigned short* src = (s_hl[r] ? J.Plo : J.Phi) + pbase + (long)s_t[r]*D2 + s_d4[r]*4;
    stg[r] = *(const uint2*)src;
  }
  const float* Wbase = J.W + (long)(w*16 + l15)*D2;
  floatx4 wv0 = *(const floatx4*)(Wbase + q*8);
  floatx4 wv1 = *(const floatx4*)(Wbase + q*8 + 4);
  #pragma unroll
  for (int r=0;r<5;r++)
    *(uint2*)&Pb[((0*2 + s_hl[r])*160 + s_t[r])*PSTR + s_d4[r]*4] = stg[r];
  __syncthreads();

  floatx4 acc[10];
  #pragma unroll
  for (int nt=0;nt<10;nt++) acc[nt] = (floatx4)0.f;

  for (int kc=0; kc<8; kc++){
    const floatx4 wc0 = wv0, wc1 = wv1;
    if (kc < 7){
      wv0 = *(const floatx4*)(Wbase + (kc+1)*32 + q*8);
      wv1 = *(const floatx4*)(Wbase + (kc+1)*32 + q*8 + 4);
      #pragma unroll
      for (int r=0;r<5;r++){
        const unsigned short* src = (s_hl[r] ? J.Plo : J.Phi) + pbase + (long)s_t[r]*D2 + (kc+1)*32 + s_d4[r]*4;
        stg[r] = *(const uint2*)src;
      }
    }
    const int d0 = kc*32 + q*8;
    const floatx4 q0 = *(const floatx4*)&Qs[d0];
    const floatx4 q1 = *(const floatx4*)&Qs[d0+4];
    union { bf16x8 v; unsigned short u[8]; } ah, al;
    #pragma unroll
    for (int j=0;j<4;j++){
      split2(wc0[j]*q0[j], ah.u[j],   al.u[j]);
      split2(wc1[j]*q1[j], ah.u[4+j], al.u[4+j]);
    }
    const int buf = kc & 1;
    #pragma unroll
    for (int nt=0;nt<10;nt++){
      const int t = nt*16 + l15;
      union { bf16x8 v; } bh, bl;
      bh.v = *(const bf16x8*)&Pb[((buf*2+0)*160 + t)*PSTR + q*8];
      bl.v = *(const bf16x8*)&Pb[((buf*2+1)*160 + t)*PSTR + q*8];
      acc[nt] = __builtin_amdgcn_mfma_f32_16x16x32_bf16(ah.v, bh.v, acc[nt], 0,0,0);
      acc[nt] = __builtin_amdgcn_mfma_f32_16x16x32_bf16(ah.v, bl.v, acc[nt], 0,0,0);
      acc[nt] = __builtin_amdgcn_mfma_f32_16x16x32_bf16(al.v, bh.v, acc[nt], 0,0,0);
    }
    if (kc < 7){
      const int nbuf = 1 - buf;
      #pragma unroll
      for (int r=0;r<5;r++)
        *(uint2*)&Pb[((nbuf*2 + s_hl[r])*160 + s_t[r])*PSTR + s_d4[r]*4] = stg[r];
      __syncthreads();
    }
  }

  float vreg[4];
  #pragma unroll
  for (int r=0;r<4;r++) vreg[r] = J.V[w*16 + q*4 + r];
  #pragma unroll
  for (int nt=0;nt<10;nt++){
    float pp = 0.f;
    #pragma unroll
    for (int r=0;r<4;r++) pp += vreg[r]*ftanh(acc[nt][r]);
    pp += __shfl_xor(pp,16);
    pp += __shfl_xor(pp,32);
    if (q==0) atomicAdd(&sc_sh[nt*16 + l15], pp);
  }
  __syncthreads();
  const float s = (tid<TT)? sc_sh[tid] : -INFINITY;
  const float a = block_softmax160_512(s, tid, red);
  if (tid < TT) J.a_out[((long)b*TT + c)*TT + tid] = a;
}

// ---------------- additive attentions (concat / minus), c-tiled LDS version ----------------
// block = (ctile 16 c's, b, job); s[c,t] = sum_k V[k] tanh(up[t,k] + sgn*uc[c,k]); softmax over t
struct AddJob { const float* up; const float* uc; const float* V; float sgn; float* a_out; };

__global__ __launch_bounds__(256) void k_addattn(AddJob j0, AddJob j1){
  const AddJob J = blockIdx.z ? j1 : j0;
  const int b = blockIdx.y, c0 = blockIdx.x*16, tid = threadIdx.x;
  const int ci = tid >> 4, tj = tid & 15;
  __shared__ float ucc[16][132];
  __shared__ float up_sh[16][132];
  __shared__ float vv[HH];
  __shared__ float sc[16][TT];
  if (tid < HH) vv[tid] = J.V[tid];
  for (int i = tid; i < 16*HH; i += 256){
    const int cc = i >> 7, k = i & 127;
    ucc[cc][k] = J.sgn * J.uc[((long)b*TT + c0 + cc)*HH + k];
  }
  __syncthreads();
  for (int tch = 0; tch < 10; tch++){
    for (int i = tid; i < 16*HH; i += 256){
      const int tt = i >> 7, k = i & 127;
      up_sh[tt][k] = J.up[((long)b*TT + tch*16 + tt)*HH + k];
    }
    __syncthreads();
    float a0 = 0.f;
    #pragma unroll 4
    for (int k = 0; k < HH; k += 4){
      const floatx4 u4 = *(const floatx4*)&up_sh[tj][k];
      const floatx4 c4 = *(const floatx4*)&ucc[ci][k];
      a0 += vv[k]*ftanh(u4[0]+c4[0]) + vv[k+1]*ftanh(u4[1]+c4[1])
          + vv[k+2]*ftanh(u4[2]+c4[2]) + vv[k+3]*ftanh(u4[3]+c4[3]);
    }
    sc[ci][tch*16 + tj] = a0;
    __syncthreads();
  }
  // softmax over t for row ci; this thread owns t = tj + 16u
  float m = -INFINITY;
  float sv[10];
  #pragma unroll
  for (int u = 0; u < 10; u++){ sv[u] = sc[ci][tj + 16*u]; m = fmaxf(m, sv[u]); }
  #pragma unroll
  for (int o = 8; o >= 1; o >>= 1) m = fmaxf(m, __shfl_xor(m, o));
  float ssum = 0.f;
  #pragma unroll
  for (int u = 0; u < 10; u++){ sv[u] = __expf(sv[u] - m); ssum += sv[u]; }
  #pragma unroll
  for (int o = 8; o >= 1; o >>= 1) ssum += __shfl_xor(ssum, o);
  const float inv = 1.f / ssum;
  float* ao = J.a_out + ((long)b*TT + c0 + ci)*TT + tj;
  #pragma unroll
  for (int u = 0; u < 10; u++) ao[16*u] = sv[u]*inv;
}

// ---------------- bilinear attention ----------------
__global__ __launch_bounds__(256) void k_bilattn(const float* hc, const float* hpWb, float* a_out){
  const int b = blockIdx.y, c = blockIdx.x, tid = threadIdx.x;
  __shared__ float hcc[D2];
  __shared__ float red[8];
  if (tid < D2) hcc[tid] = hc[((long)b*TT + c)*D2 + tid];
  __syncthreads();
  float s = -INFINITY;
  if (tid < TT){
    const float* pr = hpWb + ((long)b*TT + tid)*D2;
    float a0 = 0.f;
    #pragma unroll 4
    for (int k=0;k<D2;k++) a0 += hcc[k]*pr[k];
    s = a0;
  }
  const float a = block_softmax160(s, tid, red);
  if (tid < TT) a_out[((long)b*TT + c)*TT + tid] = a;
}

// ---------------- rep build ----------------
__global__ __launch_bounds__(256) void k_rep(const float* hp, const float* hc,
    const float* acat, const float* abil, const float* adot, const float* amin, const float* aself,
    float* aggin){
  const int b = blockIdx.y, c = blockIdx.x, tid = threadIdx.x;
  __shared__ float a5[5][TT];
  {
    const long base = ((long)b*TT + c)*TT;
    for (int i=tid;i<5*TT;i+=256){
      const int which = i/TT, t = i - which*TT;
      const float* p = which==0? acat : which==1? abil : which==2? adot : which==3? amin : aself;
      a5[which][t] = p[base + t];
    }
  }
  __syncthreads();
  const float* hpb = hp + (long)b*TT*D2 + tid;
  const float* hcb = hc + (long)b*TT*D2 + tid;
  float r0=0.f,r1=0.f,r2=0.f,r3=0.f,r4=0.f;
  for (int t=0;t<TT;t++){
    const float vp = hpb[(long)t*D2];
    const float vc = hcb[(long)t*D2];
    r0 += a5[0][t]*vp;
    r1 += a5[1][t]*vp;
    r2 += a5[2][t]*vp;
    r3 += a5[3][t]*vp;
    r4 += a5[4][t]*vc;
  }
  float* o = aggin + ((long)b*TT + c)*(6*D2);
  o[tid]        = hc[((long)b*TT + c)*D2 + tid];
  o[D2 + tid]   = r4;
  o[2*D2 + tid] = r0;
  o[3*D2 + tid] = r2;
  o[4*D2 + tid] = r1;
  o[5*D2 + tid] = r3;
}

// ---------------- tail1 ----------------
__global__ __launch_bounds__(256) void k_tail1(const float* upP, const float* Vp,
    const float* hp, float* rp){
  const int b = blockIdx.x, tid = threadIdx.x;
  __shared__ float vv[HH];
  __shared__ float ap_sh[TT];
  __shared__ float red[8];
  if (tid<HH) vv[tid] = Vp[tid];
  __syncthreads();
  float s = -INFINITY;
  if (tid<TT){
    const float* ur = upP + ((long)b*TT + tid)*HH;
    float a0=0.f;
    #pragma unroll 4
    for (int k=0;k<HH;k++) a0 += vv[k]*ftanh(ur[k]);
    s = a0;
  }
  const float a = block_softmax160(s, tid, red);
  if (tid<TT) ap_sh[tid] = a;
  __syncthreads();
  float acc = 0.f;
  const float* hpb = hp + (long)b*TT*D2 + tid;
  for (int t=0;t<TT;t++) acc += ap_sh[t]*hpb[(long)t*D2];
  rp[b*D2 + tid] = acc;
}

// ---------------- tail2 ----------------
__global__ __launch_bounds__(256) void k_tail2(const float* aggW1, const float* agg, const float* rp,
    const float* W2, const float* Vv, const float* Wout, const float* bout,
    float* out){
  const int b = blockIdx.x, tid = threadIdx.x;
  __shared__ float rps[D2];
  __shared__ float rpw[HH];
  __shared__ float ac_sh[TT];
  __shared__ float rc_sh[D2];
  __shared__ float red[8];
  if (tid < D2) rps[tid] = rp[b*D2 + tid];
  __syncthreads();
  if (tid < HH){
    float a0=0.f;
    const float* wr2 = W2 + (long)tid*D2;
    for (int d=0; d<D2; d+=4){
      const floatx4 w4 = *(const floatx4*)(wr2 + d);
      a0 += w4[0]*rps[d] + w4[1]*rps[d+1] + w4[2]*rps[d+2] + w4[3]*rps[d+3];
    }
    rpw[tid] = a0;
  }
  __syncthreads();
  float s = -INFINITY;
  if (tid < TT){
    const float* ar = aggW1 + ((long)b*TT + tid)*HH;
    float a0=0.f;
    for (int k=0;k<HH;k++) a0 += Vv[k]*(ar[k] + rpw[k]);
    s = a0;
  }
  const float a = block_softmax160(s, tid, red);
  if (tid < TT) ac_sh[tid] = a;
  __syncthreads();
  float rc=0.f;
  const float* ab = agg + (long)b*TT*D2 + tid;
  for (int t=0;t<TT;t++) rc += ac_sh[t]*ab[(long)t*D2];
  rc_sh[tid] = rc;
  __syncthreads();
  if (tid < 2){
    float o = bout[tid];
    const float* wr = Wout + (long)tid*D2;
    for (int d=0; d<D2; d++) o += wr[d]*rc_sh[d];
    out[b*2 + tid] = o;
  }
}

extern "C" void kernel_launch(void* const* d_in, const int* in_sizes, int n_in,
                              void* d_out, int out_size, void* d_ws, size_t ws_size,
                              hipStream_t stream){
  (void)in_sizes; (void)n_in; (void)out_size; (void)ws_size;
  const int* ta = (const int*)d_in[0];
  const int* tb = (const int*)d_in[1];
  const float* emb = (const float*)d_in[2];
  #define F32(i) ((const float*)d_in[i])

  float* ws = (float*)d_ws;
  float* ep    = ws;                 // 8*160*300
  float* ec    = ep    + 384000;
  float* xg_pf = ec    + 384000;     // 8*160*384 each; reused by agg stage later
  float* xg_pb = xg_pf + 491520;
  float* xg_cf = xg_pb + 491520;
  float* xg_cb = xg_cf + 491520;
  float* hp    = xg_cb + 491520;     // 8*160*256
  float* hc    = hp    + 327680;
  float* up1   = hc    + 327680;     // 8*160*128 each
  float* uc2   = up1   + 163840;
  float* ump   = uc2   + 163840;
  float* umc   = ump   + 163840;
  float* upP   = umc   + 163840;
  float* hpWb  = upP   + 163840;     // 8*160*256
  float* acat  = hpWb  + 327680;     // 8*160*160 each
  float* abil  = acat  + 204800;
  float* adot  = abil  + 204800;
  float* amin  = adot  + 204800;
  float* aself = amin  + 204800;
  float* aggin = aself + 204800;     // 8*160*1536
  float* rp    = aggin + 1966080;    // 8*256
  unsigned short* hp_hi = (unsigned short*)(rp + 2048);   // 327680 u16 each
  unsigned short* hp_lo = hp_hi + 327680;
  unsigned short* hc_hi = hp_lo + 327680;
  unsigned short* hc_lo = hc_hi + 327680;
  // pre-split weight region (ushort), padded rows
  unsigned short* wsp = hc_lo + 327680;
  unsigned short* w3h  = wsp;             unsigned short* w3l  = w3h  + 122880;  // 384x320
  unsigned short* w7h  = w3l  + 122880;   unsigned short* w7l  = w7h  + 122880;
  unsigned short* w11h = w7l  + 122880;   unsigned short* w11l = w11h + 122880;
  unsigned short* w15h = w11l + 122880;   unsigned short* w15l = w15h + 122880;
  unsigned short* w27h = w15l + 122880;   unsigned short* w27l = w27h + 32768;   // 128x256
  unsigned short* w28h = w27l + 32768;    unsigned short* w28l = w28h + 32768;
  unsigned short* w33h = w28l + 32768;    unsigned short* w33l = w33h + 32768;
  unsigned short* w37h = w33l + 32768;    unsigned short* w37l = w37h + 32768;
  unsigned short* w30h = w37l + 32768;    unsigned short* w30l = w30h + 65536;   // 256x256
  unsigned short* w19h = w30l + 65536;    unsigned short* w19l = w19h + 589824;  // 384x1536
  unsigned short* w23h = w19l + 589824;   unsigned short* w23l = w23h + 589824;
  unsigned short* w39h = w23l + 589824;   unsigned short* w39l = w39h + 32768;   // 128x256
  // dead-buffer reuse for the agg stage:
  float* xg_af = xg_pf;
  float* xg_ab = xg_pb;
  float* agg   = xg_cf;
  float* aggW1 = xg_cb;

  // 1) embedding gather + weight pre-split
  k_embed<<<dim3(3000), dim3(256), 0, stream>>>(ta, tb, emb, ep, ec);
  SplitJobs sj = {};
  sj.j[0]  = {F32(3),  w3h,  w3l,  122880, 300, 320};
  sj.j[1]  = {F32(7),  w7h,  w7l,  122880, 300, 320};
  sj.j[2]  = {F32(11), w11h, w11l, 122880, 300, 320};
  sj.j[3]  = {F32(15), w15h, w15l, 122880, 300, 320};
  sj.j[4]  = {F32(27), w27h, w27l, 32768,  256, 256};
  sj.j[5]  = {F32(28), w28h, w28l, 32768,  256, 256};
  sj.j[6]  = {F32(33), w33h, w33l, 32768,  256, 256};
  sj.j[7]  = {F32(37), w37h, w37l, 32768,  256, 256};
  sj.j[8]  = {F32(30), w30h, w30l, 65536,  256, 256};
  sj.j[9]  = {F32(19), w19h, w19l, 589824, 1536, 1536};
  sj.j[10] = {F32(23), w23h, w23l, 589824, 1536, 1536};
  sj.j[11] = {F32(39), w39h, w39l, 32768,  256, 256};
  k_splitw<<<dim3(2304,1,12), dim3(256), 0, stream>>>(sj);

  // 2) xg = x @ Wih^T + bih for p/c  (M=1280, N=384, K=300, Kp=320)
  GemmSJobs ja = {};
  ja.j[0] = {ep, w3h,  w3l,  F32(5),  xg_pf, 384, 300, 320};
  ja.j[1] = {ep, w7h,  w7l,  F32(9),  xg_pb, 384, 300, 320};
  ja.j[2] = {ec, w11h, w11l, F32(13), xg_cf, 384, 300, 320};
  ja.j[3] = {ec, w15h, w15l, F32(17), xg_cb, 384, 300, 320};
  k_gemmS<<<dim3(6,20,4), dim3(256), 0, stream>>>(ja);

  // 3) p/c GRU scans (VALU v4 — reverted to r10 best)
  GruJobs gj = {};
  gj.j[0] = {xg_pf, F32(4),  F32(6),  hp, 0,   0};
  gj.j[1] = {xg_pb, F32(8),  F32(10), hp, 128, 1};
  gj.j[2] = {xg_cf, F32(12), F32(14), hc, 0,   0};
  gj.j[3] = {xg_cb, F32(16), F32(18), hc, 128, 1};
  k_gru<<<dim3(8,4), dim3(512), 0, stream>>>(gj);

  // 3b) hi/lo split of hp & hc for pairattn B-operands
  k_splitarr<<<dim3(1280), dim3(256), 0, stream>>>(hp, hc, 327680, hp_hi, hp_lo, hc_hi, hc_lo);

  // 4) projection GEMMs (K=256)
  GemmSJobs jb = {};
  jb.j[0] = {hp, w27h, w27l, nullptr, up1,  128, 256, 256};
  jb.j[1] = {hc, w28h, w28l, nullptr, uc2,  128, 256, 256};
  jb.j[2] = {hp, w33h, w33l, nullptr, ump,  128, 256, 256};
  jb.j[3] = {hc, w33h, w33l, nullptr, umc,  128, 256, 256};
  jb.j[4] = {hp, w37h, w37l, nullptr, upP,  128, 256, 256};
  jb.j[5] = {hp, w30h, w30l, nullptr, hpWb, 256, 256, 256};
  k_gemmS<<<dim3(4,20,6), dim3(256), 0, stream>>>(jb);

  // 5) dot & self attentions (MFMA, LDS double-buffered pipeline)
  PairJob pd  = {hp_hi, hp_lo, hc, F32(31), F32(32), adot};
  PairJob psf = {hc_hi, hc_lo, hc, F32(35), F32(36), aself};
  k_pairattn<<<dim3(160,8,2), dim3(512), 0, stream>>>(pd, psf);

  // 6) concat & minus attentions (c-tiled)
  AddJob ac_ = {up1, uc2, F32(29),  1.f, acat};
  AddJob am_ = {ump, umc, F32(34), -1.f, amin};
  k_addattn<<<dim3(10,8,2), dim3(256), 0, stream>>>(ac_, am_);

  // 7) bilinear attention
  k_bilattn<<<dim3(160,8), dim3(256), 0, stream>>>(hc, hpWb, abil);

  // 8) ap/rp pooling
  k_tail1<<<dim3(8), dim3(256), 0, stream>>>(upP, F32(38), hp, rp);

  // 9) weighted reps -> agg_in
  k_rep<<<dim3(160,8), dim3(256), 0, stream>>>(hp, hc, acat, abil, adot, amin, aself, aggin);

  // 10) agg xg GEMMs (M=1280, N=384, K=1536)
  GemmSJobs jc = {};
  jc.j[0] = {aggin, w19h, w19l, F32(21), xg_af, 384, 1536, 1536};
  jc.j[1] = {aggin, w23h, w23l, F32(25), xg_ab, 384, 1536, 1536};
  k_gemmS<<<dim3(6,20,2), dim3(256), 0, stream>>>(jc);

  // 11) agg GRU scans (VALU v4)
  GruJobs gja = {};
  gja.j[0] = {xg_af, F32(20), F32(22), agg, 0,   0};
  gja.j[1] = {xg_ab, F32(24), F32(26), agg, 128, 1};
  k_gru<<<dim3(8,2), dim3(512), 0, stream>>>(gja);

  // 12) agg @ W1^T (N=128, K=256)
  GemmSJobs jd = {};
  jd.j[0] = {agg, w39h, w39l, nullptr, aggW1, 128, 256, 256};
  k_gemmS<<<dim3(2,20,1), dim3(256), 0, stream>>>(jd);

  // 13) final scores + output
  k_tail2<<<dim3(8), dim3(256), 0, stream>>>(aggW1, agg, rp, F32(40), F32(41), F32(42), F32(43),
                                             (float*)d_out);
  #undef F32
}

// Round 13
// 834.319 us; speedup vs baseline: 1.5376x; 1.0046x over previous
//
#include <hip/hip_runtime.h>

#define BB 8
#define TT 160
#define EE 300
#define HH 128
#define D2 256
#define G3 384
#define PSTR 40   // padded LDS row stride (shorts) for P tiles

typedef __attribute__((ext_vector_type(8))) short bf16x8;
typedef __attribute__((ext_vector_type(4))) float floatx4;

__device__ inline float fsigmoid(float x){ return 1.f/(1.f+__expf(-x)); }
__device__ inline float ftanh(float x){ return 2.f*fsigmoid(2.f*x) - 1.f; }

// truncation split: x ~= hi + lo, each bf16; combined rel err <= ~2^-16
__device__ inline void split2(float x, unsigned short& hi, unsigned short& lo){
  unsigned ux = __float_as_uint(x);
  hi = (unsigned short)(ux>>16);
  float r = x - __uint_as_float(ux & 0xFFFF0000u);
  lo = (unsigned short)(__float_as_uint(r)>>16);
}

// ---------------- embedding gather ----------------
__global__ __launch_bounds__(256) void k_embed(const int* ta, const int* tb,
    const float* emb, float* ep, float* ec){
  const int idx = blockIdx.x*256 + threadIdx.x;
  const int per = BB*TT*EE;
  if (idx < per){
    const int e = idx % EE, bt = idx / EE;
    ep[idx] = emb[(long)ta[bt]*EE + e];
  } else {
    const int j = idx - per;
    const int e = j % EE, bt = j / EE;
    ec[j] = emb[(long)tb[bt]*EE + e];
  }
}

// ---------------- hi/lo bf16 split of hp & hc ----------------
__global__ __launch_bounds__(256) void k_splitarr(const float* a, const float* b, int n,
    unsigned short* ahi, unsigned short* alo, unsigned short* bhi, unsigned short* blo){
  const int idx = blockIdx.x*256 + threadIdx.x;
  if (idx < n){
    split2(a[idx], ahi[idx], alo[idx]);
    split2(b[idx], bhi[idx], blo[idx]);
  }
}

// ---------------- weight pre-split: W[N x K](f32) -> hi/lo bf16 [N x Kp], zero-padded ----------------
struct SplitJob { const float* W; unsigned short* hi; unsigned short* lo; int n; int K; int Kp; };
struct SplitJobs { SplitJob j[12]; };

__global__ __launch_bounds__(256) void k_splitw(SplitJobs jobs){
  const SplitJob J = jobs.j[blockIdx.z];
  const int idx = blockIdx.x*256 + threadIdx.x;
  if (idx >= J.n) return;
  const int row = idx / J.Kp, k = idx - row*J.Kp;
  const float v = (k < J.K) ? J.W[(long)row*J.K + k] : 0.f;
  split2(v, J.hi[idx], J.lo[idx]);
}

// ---------------- MFMA GEMM with pre-split W: C = A(f32) @ W^T + bias ----------------
struct GemmSJob {
  const float* A; const unsigned short* Whi; const unsigned short* Wlo; const float* bias;
  float* C; int N; int K; int Kp;
};
struct GemmSJobs { GemmSJob j[6]; };

__global__ __launch_bounds__(256) void k_gemmS(GemmSJobs jobs){
  const GemmSJob J = jobs.j[blockIdx.z];
  const int tid = threadIdx.x;
  const int lane = tid & 63, w = tid >> 6;
  const int l15 = lane & 15, q = lane >> 4;
  const int n0 = blockIdx.x * 64;
  if (n0 >= J.N) return;
  const int K = J.K, Kp = J.Kp;
  const long mrow = blockIdx.y*64 + w*16 + l15;
  const float* Arow = J.A + mrow*K;
  floatx4 acc[4];
  #pragma unroll
  for (int t=0;t<4;t++) acc[t] = (floatx4)0.f;
  const int nch = (K+31)>>5;
  for (int kc=0; kc<nch; kc++){
    const int k0 = kc<<5;
    const int kb = k0 + q*8;
    float av[8];
    if (k0+32 <= K){
      const floatx4 a0 = *(const floatx4*)(Arow+kb);
      const floatx4 a1 = *(const floatx4*)(Arow+kb+4);
      av[0]=a0[0];av[1]=a0[1];av[2]=a0[2];av[3]=a0[3];
      av[4]=a1[0];av[5]=a1[1];av[6]=a1[2];av[7]=a1[3];
    } else {
      #pragma unroll
      for (int j=0;j<8;j++){ const int k=kb+j; av[j] = (k<K)? Arow[k] : 0.f; }
    }
    union { bf16x8 v; unsigned short u[8]; } ahi, alo;
    #pragma unroll
    for (int j=0;j<8;j++) split2(av[j], ahi.u[j], alo.u[j]);
    #pragma unroll
    for (int t=0;t<4;t++){
      const int n = n0 + t*16 + l15;
      const long wo = (long)n*Kp + kb;
      union { bf16x8 v; uint4 d; } whi, wlo;
      whi.d = *(const uint4*)(J.Whi + wo);
      wlo.d = *(const uint4*)(J.Wlo + wo);
      acc[t] = __builtin_amdgcn_mfma_f32_16x16x32_bf16(ahi.v, whi.v, acc[t], 0,0,0);
      acc[t] = __builtin_amdgcn_mfma_f32_16x16x32_bf16(ahi.v, wlo.v, acc[t], 0,0,0);
      acc[t] = __builtin_amdgcn_mfma_f32_16x16x32_bf16(alo.v, whi.v, acc[t], 0,0,0);
    }
  }
  const long rbase = blockIdx.y*64 + w*16 + q*4;
  #pragma unroll
  for (int t=0;t<4;t++){
    const int n = n0 + t*16 + l15;
    const float bv = J.bias ? J.bias[n] : 0.f;
    #pragma unroll
    for (int r=0;r<4;r++)
      J.C[(rbase+r)*(long)J.N + n] = acc[t][r] + bv;
  }
}

// ---------------- GRU scan v4: 512 threads, 4 threads per h-unit ----------------
struct GruJob { const float* xg; const float* Whh; const float* bhh; float* out; int ocol; int rev; };
struct GruJobs { GruJob j[4]; };

__global__ __launch_bounds__(512,1) void k_gru(GruJobs jobs){
  const GruJob J = jobs.j[blockIdx.y];
  const int bi = blockIdx.x;
  const int tid = threadIdx.x;
  const int j = tid >> 2, p = tid & 3;
  __shared__ float xgt[16][G3];
  __shared__ float hbuf[16][HH];
  __shared__ float hcur[2][HH];
  float wr[32], wz[32], wn[32];
  {
    const float* r0 = J.Whh + (long)j*HH + p*32;
    const float* z0 = J.Whh + (long)(HH+j)*HH + p*32;
    const float* n0 = J.Whh + (long)(2*HH+j)*HH + p*32;
    #pragma unroll
    for (int k=0;k<32;k+=4){
      *(floatx4*)&wr[k] = *(const floatx4*)(r0+k);
      *(floatx4*)&wz[k] = *(const floatx4*)(z0+k);
      *(floatx4*)&wn[k] = *(const floatx4*)(n0+k);
    }
  }
  float bhr=0.f,bhz=0.f,bhn=0.f;
  if (p==0){ bhr = J.bhh[j]; bhz = J.bhh[HH+j]; bhn = J.bhh[2*HH+j]; }
  if (tid < 256) ((float*)hcur)[tid] = 0.f;
  float hreg = 0.f;
  __syncthreads();

  for (int s0=0; s0<TT; s0+=16){
    #pragma unroll
    for (int r=0;r<3;r++){
      const int i = r*512 + tid;
      const int row = i/96, c4 = i - row*96;
      const int tt = J.rev ? (TT-1-(s0+row)) : (s0+row);
      *(floatx4*)&xgt[row][c4*4] = *(const floatx4*)(J.xg + ((long)bi*TT + tt)*G3 + c4*4);
    }
    __syncthreads();
    for (int si=0; si<16; si++){
      const int s = s0 + si;
      const int buf = s & 1;
      float cxr=0.f,cxz=0.f,cxn=0.f;
      if (p==0){ cxr = xgt[si][j]; cxz = xgt[si][HH+j]; cxn = xgt[si][2*HH+j]; }
      float ar=0.f, az=0.f, an=0.f;
      #pragma unroll
      for (int k=0;k<32;k+=4){
        const floatx4 h4 = *(const floatx4*)&hcur[buf][p*32+k];
        ar += wr[k]*h4[0] + wr[k+1]*h4[1] + wr[k+2]*h4[2] + wr[k+3]*h4[3];
        az += wz[k]*h4[0] + wz[k+1]*h4[1] + wz[k+2]*h4[2] + wz[k+3]*h4[3];
        an += wn[k]*h4[0] + wn[k+1]*h4[1] + wn[k+2]*h4[2] + wn[k+3]*h4[3];
      }
      ar += __shfl_xor(ar,1); ar += __shfl_xor(ar,2);
      az += __shfl_xor(az,1); az += __shfl_xor(az,2);
      an += __shfl_xor(an,1); an += __shfl_xor(an,2);
      if (p==0){
        const float gr = fsigmoid(cxr + ar + bhr);
        const float gz = fsigmoid(cxz + az + bhz);
        const float gn = ftanh  (cxn + gr*(an + bhn));
        const float h = (1.f-gz)*gn + gz*hreg;
        hreg = h;
        hcur[1-buf][j] = h;
        hbuf[si][j] = h;
      }
      __syncthreads();
    }
    {
      const int row = tid >> 5, c4 = tid & 31;
      const int tt = J.rev ? (TT-1-(s0+row)) : (s0+row);
      *(floatx4*)(J.out + ((long)bi*TT + tt)*D2 + J.ocol + c4*4) = *(const floatx4*)&hbuf[row][c4*4];
    }
  }
}

// ---------------- block softmax over 160 values (256 threads) ----------------
__device__ inline float block_softmax160(float s, int tid, float* red){
  float m = s;
  #pragma unroll
  for (int o=32;o>0;o>>=1) m = fmaxf(m, __shfl_xor(m,o));
  if ((tid&63)==0) red[tid>>6] = m;
  __syncthreads();
  m = fmaxf(fmaxf(red[0],red[1]), fmaxf(red[2],red[3]));
  const float p = (tid<TT) ? __expf(s-m) : 0.f;
  float t = p;
  #pragma unroll
  for (int o=32;o>0;o>>=1) t += __shfl_xor(t,o);
  if ((tid&63)==0) red[4+(tid>>6)] = t;
  __syncthreads();
  const float sum = red[4]+red[5]+red[6]+red[7];
  return p / sum;
}

// ---------------- pairwise product attention (dot & self), MFMA + LDS pipeline, CTILE=2 ----------------
// Per block: two c's share the staged P hi/lo fragments -> ds_read count halves.
struct PairJob { const unsigned short* Phi; const unsigned short* Plo;
                 const float* Q; const float* W; const float* V; float* a_out; };

__global__ __launch_bounds__(512) void k_pairattn(PairJob j0, PairJob j1){
  const PairJob J = blockIdx.z ? j1 : j0;
  const int b = blockIdx.y, c0 = blockIdx.x*2;
  const int tid = threadIdx.x;
  const int lane = tid & 63, w = tid >> 6;
  const int l15 = lane & 15, q = lane >> 4;
  __shared__ unsigned short Pb[2*2*160*PSTR];
  __shared__ float Qs[2][D2];
  __shared__ float sc_sh[2][TT];
  __shared__ float red[16];
  {
    const int row = tid >> 8, col = tid & 255;
    Qs[row][col] = J.Q[((long)b*TT + c0 + row)*D2 + col];
  }
  if (tid < 2*TT) ((float*)sc_sh)[tid] = 0.f;
  const long pbase = (long)b*TT*D2;

  // per-thread staging (5 x uint2 = 20480 B per chunk); pointers hoisted
  const unsigned short* srcp[5];
  unsigned short* dstp[5];
  #pragma unroll
  for (int r=0;r<5;r++){
    const int idx = tid + r*512;
    const int hl = (idx >= 1280) ? 1 : 0;
    const int e4 = idx - hl*1280;
    const int st = e4 >> 3, sd4 = e4 & 7;
    srcp[r] = (hl ? J.Plo : J.Phi) + pbase + (long)st*D2 + sd4*4;
    dstp[r] = &Pb[((0*2 + hl)*160 + st)*PSTR + sd4*4];
  }
  uint2 stg[5];
  #pragma unroll
  for (int r=0;r<5;r++) stg[r] = *(const uint2*)(srcp[r]);
  const float* Wbase = J.W + (long)(w*16 + l15)*D2;
  floatx4 wv0 = *(const floatx4*)(Wbase + q*8);
  floatx4 wv1 = *(const floatx4*)(Wbase + q*8 + 4);
  #pragma unroll
  for (int r=0;r<5;r++) *(uint2*)(dstp[r]) = stg[r];
  __syncthreads();

  floatx4 acc0[10], acc1[10];
  #pragma unroll
  for (int nt=0;nt<10;nt++){ acc0[nt] = (floatx4)0.f; acc1[nt] = (floatx4)0.f; }

  for (int kc=0; kc<8; kc++){
    const floatx4 wc0 = wv0, wc1 = wv1;
    if (kc < 7){
      wv0 = *(const floatx4*)(Wbase + (kc+1)*32 + q*8);
      wv1 = *(const floatx4*)(Wbase + (kc+1)*32 + q*8 + 4);
      #pragma unroll
      for (int r=0;r<5;r++) stg[r] = *(const uint2*)(srcp[r] + (kc+1)*32);
    }
    const int d0 = kc*32 + q*8;
    const floatx4 q00 = *(const floatx4*)&Qs[0][d0];
    const floatx4 q01 = *(const floatx4*)&Qs[0][d0+4];
    const floatx4 q10 = *(const floatx4*)&Qs[1][d0];
    const floatx4 q11 = *(const floatx4*)&Qs[1][d0+4];
    union { bf16x8 v; unsigned short u[8]; } ah0, al0, ah1, al1;
    #pragma unroll
    for (int j=0;j<4;j++){
      split2(wc0[j]*q00[j], ah0.u[j],   al0.u[j]);
      split2(wc1[j]*q01[j], ah0.u[4+j], al0.u[4+j]);
      split2(wc0[j]*q10[j], ah1.u[j],   al1.u[j]);
      split2(wc1[j]*q11[j], ah1.u[4+j], al1.u[4+j]);
    }
    const int buf = kc & 1;
    #pragma unroll
    for (int nt=0;nt<10;nt++){
      const int t = nt*16 + l15;
      union { bf16x8 v; } bh, bl;
      bh.v = *(const bf16x8*)&Pb[((buf*2+0)*160 + t)*PSTR + q*8];
      bl.v = *(const bf16x8*)&Pb[((buf*2+1)*160 + t)*PSTR + q*8];
      acc0[nt] = __builtin_amdgcn_mfma_f32_16x16x32_bf16(ah0.v, bh.v, acc0[nt], 0,0,0);
      acc0[nt] = __builtin_amdgcn_mfma_f32_16x16x32_bf16(ah0.v, bl.v, acc0[nt], 0,0,0);
      acc0[nt] = __builtin_amdgcn_mfma_f32_16x16x32_bf16(al0.v, bh.v, acc0[nt], 0,0,0);
      acc1[nt] = __builtin_amdgcn_mfma_f32_16x16x32_bf16(ah1.v, bh.v, acc1[nt], 0,0,0);
      acc1[nt] = __builtin_amdgcn_mfma_f32_16x16x32_bf16(ah1.v, bl.v, acc1[nt], 0,0,0);
      acc1[nt] = __builtin_amdgcn_mfma_f32_16x16x32_bf16(al1.v, bh.v, acc1[nt], 0,0,0);
    }
    if (kc < 7){
      const int nbuf = 1 - buf;
      #pragma unroll
      for (int r=0;r<5;r++) *(uint2*)(dstp[r] + nbuf*(2*160*PSTR)) = stg[r];
      __syncthreads();
    }
  }

  float vreg[4];
  #pragma unroll
  for (int r=0;r<4;r++) vreg[r] = J.V[w*16 + q*4 + r];
  #pragma unroll
  for (int nt=0;nt<10;nt++){
    float p0 = 0.f, p1 = 0.f;
    #pragma unroll
    for (int r=0;r<4;r++){
      p0 += vreg[r]*ftanh(acc0[nt][r]);
      p1 += vreg[r]*ftanh(acc1[nt][r]);
    }
    p0 += __shfl_xor(p0,16); p0 += __shfl_xor(p0,32);
    p1 += __shfl_xor(p1,16); p1 += __shfl_xor(p1,32);
    if (q==0){
      atomicAdd(&sc_sh[0][nt*16 + l15], p0);
      atomicAdd(&sc_sh[1][nt*16 + l15], p1);
    }
  }
  __syncthreads();
  // two-row softmax: threads 0..255 row 0, 256..511 row 1 (4 waves each)
  {
    const int row = tid >> 8, t_ = tid & 255;
    float s = (t_ < TT) ? sc_sh[row][t_] : -INFINITY;
    float m = s;
    #pragma unroll
    for (int o=32;o>0;o>>=1) m = fmaxf(m, __shfl_xor(m,o));
    if (lane==0) red[w] = m;
    __syncthreads();
    m = fmaxf(fmaxf(red[row*4+0],red[row*4+1]), fmaxf(red[row*4+2],red[row*4+3]));
    const float p = (t_ < TT) ? __expf(s-m) : 0.f;
    float su = p;
    #pragma unroll
    for (int o=32;o>0;o>>=1) su += __shfl_xor(su,o);
    if (lane==0) red[8+w] = su;
    __syncthreads();
    const float ssum = red[8+row*4+0]+red[8+row*4+1]+red[8+row*4+2]+red[8+row*4+3];
    if (t_ < TT) J.a_out[((long)b*TT + c0 + row)*TT + t_] = p/ssum;
  }
}

// ---------------- additive attentions (concat / minus), c-tiled LDS version ----------------
struct AddJob { const float* up; const float* uc; const float* V; float sgn; float* a_out; };

__global__ __launch_bounds__(256) void k_addattn(AddJob j0, AddJob j1){
  const AddJob J = blockIdx.z ? j1 : j0;
  const int b = blockIdx.y, c0 = blockIdx.x*16, tid = threadIdx.x;
  const int ci = tid >> 4, tj = tid & 15;
  __shared__ float ucc[16][132];
  __shared__ float up_sh[16][132];
  __shared__ float vv[HH];
  __shared__ float sc[16][TT];
  if (tid < HH) vv[tid] = J.V[tid];
  for (int i = tid; i < 16*HH; i += 256){
    const int cc = i >> 7, k = i & 127;
    ucc[cc][k] = J.sgn * J.uc[((long)b*TT + c0 + cc)*HH + k];
  }
  __syncthreads();
  for (int tch = 0; tch < 10; tch++){
    for (int i = tid; i < 16*HH; i += 256){
      const int tt = i >> 7, k = i & 127;
      up_sh[tt][k] = J.up[((long)b*TT + tch*16 + tt)*HH + k];
    }
    __syncthreads();
    float a0 = 0.f;
    #pragma unroll 4
    for (int k = 0; k < HH; k += 4){
      const floatx4 u4 = *(const floatx4*)&up_sh[tj][k];
      const floatx4 c4 = *(const floatx4*)&ucc[ci][k];
      a0 += vv[k]*ftanh(u4[0]+c4[0]) + vv[k+1]*ftanh(u4[1]+c4[1])
          + vv[k+2]*ftanh(u4[2]+c4[2]) + vv[k+3]*ftanh(u4[3]+c4[3]);
    }
    sc[ci][tch*16 + tj] = a0;
    __syncthreads();
  }
  float m = -INFINITY;
  float sv[10];
  #pragma unroll
  for (int u = 0; u < 10; u++){ sv[u] = sc[ci][tj + 16*u]; m = fmaxf(m, sv[u]); }
  #pragma unroll
  for (int o = 8; o >= 1; o >>= 1) m = fmaxf(m, __shfl_xor(m, o));
  float ssum = 0.f;
  #pragma unroll
  for (int u = 0; u < 10; u++){ sv[u] = __expf(sv[u] - m); ssum += sv[u]; }
  #pragma unroll
  for (int o = 8; o >= 1; o >>= 1) ssum += __shfl_xor(ssum, o);
  const float inv = 1.f / ssum;
  float* ao = J.a_out + ((long)b*TT + c0 + ci)*TT + tj;
  #pragma unroll
  for (int u = 0; u < 10; u++) ao[16*u] = sv[u]*inv;
}

// ---------------- bilinear attention ----------------
__global__ __launch_bounds__(256) void k_bilattn(const float* hc, const float* hpWb, float* a_out){
  const int b = blockIdx.y, c = blockIdx.x, tid = threadIdx.x;
  __shared__ float hcc[D2];
  __shared__ float red[8];
  if (tid < D2) hcc[tid] = hc[((long)b*TT + c)*D2 + tid];
  __syncthreads();
  float s = -INFINITY;
  if (tid < TT){
    const float* pr = hpWb + ((long)b*TT + tid)*D2;
    float a0 = 0.f;
    #pragma unroll 4
    for (int k=0;k<D2;k++) a0 += hcc[k]*pr[k];
    s = a0;
  }
  const float a = block_softmax160(s, tid, red);
  if (tid < TT) a_out[((long)b*TT + c)*TT + tid] = a;
}

// ---------------- rep build ----------------
__global__ __launch_bounds__(256) void k_rep(const float* hp, const float* hc,
    const float* acat, const float* abil, const float* adot, const float* amin, const float* aself,
    float* aggin){
  const int b = blockIdx.y, c = blockIdx.x, tid = threadIdx.x;
  __shared__ float a5[5][TT];
  {
    const long base = ((long)b*TT + c)*TT;
    for (int i=tid;i<5*TT;i+=256){
      const int which = i/TT, t = i - which*TT;
      const float* p = which==0? acat : which==1? abil : which==2? adot : which==3? amin : aself;
      a5[which][t] = p[base + t];
    }
  }
  __syncthreads();
  const float* hpb = hp + (long)b*TT*D2 + tid;
  const float* hcb = hc + (long)b*TT*D2 + tid;
  float r0=0.f,r1=0.f,r2=0.f,r3=0.f,r4=0.f;
  for (int t=0;t<TT;t++){
    const float vp = hpb[(long)t*D2];
    const float vc = hcb[(long)t*D2];
    r0 += a5[0][t]*vp;
    r1 += a5[1][t]*vp;
    r2 += a5[2][t]*vp;
    r3 += a5[3][t]*vp;
    r4 += a5[4][t]*vc;
  }
  float* o = aggin + ((long)b*TT + c)*(6*D2);
  o[tid]        = hc[((long)b*TT + c)*D2 + tid];
  o[D2 + tid]   = r4;
  o[2*D2 + tid] = r0;
  o[3*D2 + tid] = r2;
  o[4*D2 + tid] = r1;
  o[5*D2 + tid] = r3;
}

// ---------------- tail1 ----------------
__global__ __launch_bounds__(256) void k_tail1(const float* upP, const float* Vp,
    const float* hp, float* rp){
  const int b = blockIdx.x, tid = threadIdx.x;
  __shared__ float vv[HH];
  __shared__ float ap_sh[TT];
  __shared__ float red[8];
  if (tid<HH) vv[tid] = Vp[tid];
  __syncthreads();
  float s = -INFINITY;
  if (tid<TT){
    const float* ur = upP + ((long)b*TT + tid)*HH;
    float a0=0.f;
    #pragma unroll 4
    for (int k=0;k<HH;k++) a0 += vv[k]*ftanh(ur[k]);
    s = a0;
  }
  const float a = block_softmax160(s, tid, red);
  if (tid<TT) ap_sh[tid] = a;
  __syncthreads();
  float acc = 0.f;
  const float* hpb = hp + (long)b*TT*D2 + tid;
  for (int t=0;t<TT;t++) acc += ap_sh[t]*hpb[(long)t*D2];
  rp[b*D2 + tid] = acc;
}

// ---------------- tail2 ----------------
__global__ __launch_bounds__(256) void k_tail2(const float* aggW1, const float* agg, const float* rp,
    const float* W2, const float* Vv, const float* Wout, const float* bout,
    float* out){
  const int b = blockIdx.x, tid = threadIdx.x;
  __shared__ float rps[D2];
  __shared__ float rpw[HH];
  __shared__ float ac_sh[TT];
  __shared__ float rc_sh[D2];
  __shared__ float red[8];
  if (tid < D2) rps[tid] = rp[b*D2 + tid];
  __syncthreads();
  if (tid < HH){
    float a0=0.f;
    const float* wr2 = W2 + (long)tid*D2;
    for (int d=0; d<D2; d+=4){
      const floatx4 w4 = *(const floatx4*)(wr2 + d);
      a0 += w4[0]*rps[d] + w4[1]*rps[d+1] + w4[2]*rps[d+2] + w4[3]*rps[d+3];
    }
    rpw[tid] = a0;
  }
  __syncthreads();
  float s = -INFINITY;
  if (tid < TT){
    const float* ar = aggW1 + ((long)b*TT + tid)*HH;
    float a0=0.f;
    for (int k=0;k<HH;k++) a0 += Vv[k]*(ar[k] + rpw[k]);
    s = a0;
  }
  const float a = block_softmax160(s, tid, red);
  if (tid < TT) ac_sh[tid] = a;
  __syncthreads();
  float rc=0.f;
  const float* ab = agg + (long)b*TT*D2 + tid;
  for (int t=0;t<TT;t++) rc += ac_sh[t]*ab[(long)t*D2];
  rc_sh[tid] = rc;
  __syncthreads();
  if (tid < 2){
    float o = bout[tid];
    const float* wr = Wout + (long)tid*D2;
    for (int d=0; d<D2; d++) o += wr[d]*rc_sh[d];
    out[b*2 + tid] = o;
  }
}

extern "C" void kernel_launch(void* const* d_in, const int* in_sizes, int n_in,
                              void* d_out, int out_size, void* d_ws, size_t ws_size,
                              hipStream_t stream){
  (void)in_sizes; (void)n_in; (void)out_size; (void)ws_size;
  const int* ta = (const int*)d_in[0];
  const int* tb = (const int*)d_in[1];
  const float* emb = (const float*)d_in[2];
  #define F32(i) ((const float*)d_in[i])

  float* ws = (float*)d_ws;
  float* ep    = ws;                 // 8*160*300
  float* ec    = ep    + 384000;
  float* xg_pf = ec    + 384000;     // 8*160*384 each; reused by agg stage later
  float* xg_pb = xg_pf + 491520;
  float* xg_cf = xg_pb + 491520;
  float* xg_cb = xg_cf + 491520;
  float* hp    = xg_cb + 491520;     // 8*160*256
  float* hc    = hp    + 327680;
  float* up1   = hc    + 327680;     // 8*160*128 each
  float* uc2   = up1   + 163840;
  float* ump   = uc2   + 163840;
  float* umc   = ump   + 163840;
  float* upP   = umc   + 163840;
  float* hpWb  = upP   + 163840;     // 8*160*256
  float* acat  = hpWb  + 327680;     // 8*160*160 each
  float* abil  = acat  + 204800;
  float* adot  = abil  + 204800;
  float* amin  = adot  + 204800;
  float* aself = amin  + 204800;
  float* aggin = aself + 204800;     // 8*160*1536
  float* rp    = aggin + 1966080;    // 8*256
  unsigned short* hp_hi = (unsigned short*)(rp + 2048);   // 327680 u16 each
  unsigned short* hp_lo = hp_hi + 327680;
  unsigned short* hc_hi = hp_lo + 327680;
  unsigned short* hc_lo = hc_hi + 327680;
  // pre-split weight region (ushort), padded rows
  unsigned short* wsp = hc_lo + 327680;
  unsigned short* w3h  = wsp;             unsigned short* w3l  = w3h  + 122880;  // 384x320
  unsigned short* w7h  = w3l  + 122880;   unsigned short* w7l  = w7h  + 122880;
  unsigned short* w11h = w7l  + 122880;   unsigned short* w11l = w11h + 122880;
  unsigned short* w15h = w11l + 122880;   unsigned short* w15l = w15h + 122880;
  unsigned short* w27h = w15l + 122880;   unsigned short* w27l = w27h + 32768;   // 128x256
  unsigned short* w28h = w27l + 32768;    unsigned short* w28l = w28h + 32768;
  unsigned short* w33h = w28l + 32768;    unsigned short* w33l = w33h + 32768;
  unsigned short* w37h = w33l + 32768;    unsigned short* w37l = w37h + 32768;
  unsigned short* w30h = w37l + 32768;    unsigned short* w30l = w30h + 65536;   // 256x256
  unsigned short* w19h = w30l + 65536;    unsigned short* w19l = w19h + 589824;  // 384x1536
  unsigned short* w23h = w19l + 589824;   unsigned short* w23l = w23h + 589824;
  unsigned short* w39h = w23l + 589824;   unsigned short* w39l = w39h + 32768;   // 128x256
  // dead-buffer reuse for the agg stage:
  float* xg_af = xg_pf;
  float* xg_ab = xg_pb;
  float* agg   = xg_cf;
  float* aggW1 = xg_cb;

  // 1) embedding gather + weight pre-split
  k_embed<<<dim3(3000), dim3(256), 0, stream>>>(ta, tb, emb, ep, ec);
  SplitJobs sj = {};
  sj.j[0]  = {F32(3),  w3h,  w3l,  122880, 300, 320};
  sj.j[1]  = {F32(7),  w7h,  w7l,  122880, 300, 320};
  sj.j[2]  = {F32(11), w11h, w11l, 122880, 300, 320};
  sj.j[3]  = {F32(15), w15h, w15l, 122880, 300, 320};
  sj.j[4]  = {F32(27), w27h, w27l, 32768,  256, 256};
  sj.j[5]  = {F32(28), w28h, w28l, 32768,  256, 256};
  sj.j[6]  = {F32(33), w33h, w33l, 32768,  256, 256};
  sj.j[7]  = {F32(37), w37h, w37l, 32768,  256, 256};
  sj.j[8]  = {F32(30), w30h, w30l, 65536,  256, 256};
  sj.j[9]  = {F32(19), w19h, w19l, 589824, 1536, 1536};
  sj.j[10] = {F32(23), w23h, w23l, 589824, 1536, 1536};
  sj.j[11] = {F32(39), w39h, w39l, 32768,  256, 256};
  k_splitw<<<dim3(2304,1,12), dim3(256), 0, stream>>>(sj);

  // 2) xg = x @ Wih^T + bih for p/c  (M=1280, N=384, K=300, Kp=320)
  GemmSJobs ja = {};
  ja.j[0] = {ep, w3h,  w3l,  F32(5),  xg_pf, 384, 300, 320};
  ja.j[1] = {ep, w7h,  w7l,  F32(9),  xg_pb, 384, 300, 320};
  ja.j[2] = {ec, w11h, w11l, F32(13), xg_cf, 384, 300, 320};
  ja.j[3] = {ec, w15h, w15l, F32(17), xg_cb, 384, 300, 320};
  k_gemmS<<<dim3(6,20,4), dim3(256), 0, stream>>>(ja);

  // 3) p/c GRU scans (VALU v4)
  GruJobs gj = {};
  gj.j[0] = {xg_pf, F32(4),  F32(6),  hp, 0,   0};
  gj.j[1] = {xg_pb, F32(8),  F32(10), hp, 128, 1};
  gj.j[2] = {xg_cf, F32(12), F32(14), hc, 0,   0};
  gj.j[3] = {xg_cb, F32(16), F32(18), hc, 128, 1};
  k_gru<<<dim3(8,4), dim3(512), 0, stream>>>(gj);

  // 3b) hi/lo split of hp & hc for pairattn B-operands
  k_splitarr<<<dim3(1280), dim3(256), 0, stream>>>(hp, hc, 327680, hp_hi, hp_lo, hc_hi, hc_lo);

  // 4) projection GEMMs (K=256)
  GemmSJobs jb = {};
  jb.j[0] = {hp, w27h, w27l, nullptr, up1,  128, 256, 256};
  jb.j[1] = {hc, w28h, w28l, nullptr, uc2,  128, 256, 256};
  jb.j[2] = {hp, w33h, w33l, nullptr, ump,  128, 256, 256};
  jb.j[3] = {hc, w33h, w33l, nullptr, umc,  128, 256, 256};
  jb.j[4] = {hp, w37h, w37l, nullptr, upP,  128, 256, 256};
  jb.j[5] = {hp, w30h, w30l, nullptr, hpWb, 256, 256, 256};
  k_gemmS<<<dim3(4,20,6), dim3(256), 0, stream>>>(jb);

  // 5) dot & self attentions (MFMA, LDS pipeline, CTILE=2)
  PairJob pd  = {hp_hi, hp_lo, hc, F32(31), F32(32), adot};
  PairJob psf = {hc_hi, hc_lo, hc, F32(35), F32(36), aself};
  k_pairattn<<<dim3(80,8,2), dim3(512), 0, stream>>>(pd, psf);

  // 6) concat & minus attentions (c-tiled)
  AddJob ac_ = {up1, uc2, F32(29),  1.f, acat};
  AddJob am_ = {ump, umc, F32(34), -1.f, amin};
  k_addattn<<<dim3(10,8,2), dim3(256), 0, stream>>>(ac_, am_);

  // 7) bilinear attention
  k_bilattn<<<dim3(160,8), dim3(256), 0, stream>>>(hc, hpWb, abil);

  // 8) ap/rp pooling
  k_tail1<<<dim3(8), dim3(256), 0, stream>>>(upP, F32(38), hp, rp);

  // 9) weighted reps -> agg_in
  k_rep<<<dim3(160,8), dim3(256), 0, stream>>>(hp, hc, acat, abil, adot, amin, aself, aggin);

  // 10) agg xg GEMMs (M=1280, N=384, K=1536)
  GemmSJobs jc = {};
  jc.j[0] = {aggin, w19h, w19l, F32(21), xg_af, 384, 1536, 1536};
  jc.j[1] = {aggin, w23h, w23l, F32(25), xg_ab, 384, 1536, 1536};
  k_gemmS<<<dim3(6,20,2), dim3(256), 0, stream>>>(jc);

  // 11) agg GRU scans (VALU v4)
  GruJobs gja = {};
  gja.j[0] = {xg_af, F32(20), F32(22), agg, 0,   0};
  gja.j[1] = {xg_ab, F32(24), F32(26), agg, 128, 1};
  k_gru<<<dim3(8,2), dim3(512), 0, stream>>>(gja);

  // 12) agg @ W1^T (N=128, K=256)
  GemmSJobs jd = {};
  jd.j[0] = {agg, w39h, w39l, nullptr, aggW1, 128, 256, 256};
  k_gemmS<<<dim3(2,20,1), dim3(256), 0, stream>>>(jd);

  // 13) final scores + output
  k_tail2<<<dim3(8), dim3(256), 0, stream>>>(aggW1, agg, rp, F32(40), F32(41), F32(42), F32(43),
                                             (float*)d_out);
  #undef F32
}